// Round 22
// baseline (1104.496 us; speedup 1.0000x reference)
//
#include <hip/hip_runtime.h>
#include <hip/hip_bf16.h>

// Problem dims
constexpr int B_  = 16;
constexpr int N_  = 64;     // stations
constexpr int T_  = 168;    // seq
constexpr int F_  = 8;      // raw features
constexpr int E_  = 256;    // dmodel
constexpr int H_  = 8;      // heads
constexpr int DH_ = 32;     // head dim
constexpr int NT_ = N_ * T_;           // 10752 (rows per batch)
constexpr int LDQ_ = 768;              // interleaved Q|K|V row stride
constexpr int BT_ = B_ * T_;           // 2688 embedding rows

typedef __bf16 bf16x8 __attribute__((ext_vector_type(8)));
typedef float  f32x4  __attribute__((ext_vector_type(4)));
typedef float  f32x4u __attribute__((ext_vector_type(4), aligned(4)));

__device__ __forceinline__ unsigned short f2b(float f) {
  union { float f; unsigned int u; } v; v.f = f;
  unsigned int r = (v.u + 0x7FFFu + ((v.u >> 16) & 1u)) >> 16;
  return (unsigned short)r;
}
__device__ __forceinline__ float b2f(unsigned short h) {
  union { unsigned int u; float f; } v; v.u = ((unsigned int)h) << 16;
  return v.f;
}
__device__ __forceinline__ unsigned int cvtpk(float lo, float hi) {
  unsigned int r;
  asm("v_cvt_pk_bf16_f32 %0, %1, %2" : "=v"(r) : "v"(lo), "v"(hi));
  return r;
}
__device__ __forceinline__ void gload16(const void* g, void* l) {
  __builtin_amdgcn_global_load_lds(
      (const __attribute__((address_space(1))) unsigned int*)g,
      (__attribute__((address_space(3))) unsigned int*)l, 16, 0, 0);
}

// ---------------------------------------------------------------------------
// adjacency  a[b][m][n] = 0.5*(w_norm[m][n] + (m==n))
// ---------------------------------------------------------------------------
__global__ void adj_kernel(const float* __restrict__ locs, float* __restrict__ a) {
  int b = blockIdx.x;
  int m = threadIdx.x;  // 64 threads
  __shared__ float lx[64], ly[64];
  lx[m] = locs[(b * 64 + m) * 2 + 0];
  ly[m] = locs[(b * 64 + m) * 2 + 1];
  __syncthreads();
  float x = lx[m], y = ly[m];
  float sum = 0.f;
  for (int n = 0; n < 64; ++n) {
    float dx = x - lx[n], dy = y - ly[n];
    float d = sqrtf(dx * dx + dy * dy + 1e-12f);
    sum += (n == m) ? 0.f : 1.f / d;
  }
  float inv = 0.5f / sum;
  for (int n = 0; n < 64; ++n) {
    float dx = x - lx[n], dy = y - ly[n];
    float d = sqrtf(dx * dx + dy * dy + 1e-12f);
    float w = (n == m) ? 0.5f : inv / d;
    a[(b * 64 + m) * 64 + n] = w;
  }
}

// ---------------------------------------------------------------------------
// weight convert: in f32 [K][N] (ld N) -> outT bf16 [Np][Kp] (ld Kp), zero pad
// ---------------------------------------------------------------------------
__global__ void convw_kernel(const float* __restrict__ in, unsigned short* __restrict__ outT,
                             int K, int N, int Kp, int Np) {
  int idx = blockIdx.x * 256 + threadIdx.x;
  if (idx >= Np * Kp) return;
  int n = idx / Kp, k = idx % Kp;
  float v = (k < K && n < N) ? in[(long)k * N + n] : 0.f;
  outT[idx] = f2b(v);
}

// ---------------------------------------------------------------------------
// elementwise f32 -> bf16
// ---------------------------------------------------------------------------
__global__ void cvtb_kernel(const float* __restrict__ in, unsigned short* __restrict__ out,
                            int n) {
  int i = blockIdx.x * 256 + threadIdx.x;
  if (i < n) out[i] = f2b(in[i]);
}

// ---------------------------------------------------------------------------
// broadcast bv into perqv cols 512..767 for all BT rows
// ---------------------------------------------------------------------------
__global__ void bvfill_kernel(const float* __restrict__ bv, float* __restrict__ perqv) {
  int r = blockIdx.x, j = threadIdx.x;
  perqv[(long)r * 768 + 512 + j] = bv[j];
}

// ---------------------------------------------------------------------------
// FUSED GCN + fc1 for one (b,t): computes G=relu(xa@gcn_w+b) into a 32KB LDS
// tile (granule-XOR layout) and immediately runs the fc1 MFMA on it, writing
// tokb[:,8:256] (+pos). tokb[:,0:8] = x + pos. Kills the global G round-trip.
// 256 threads (4 waves). Rows of the block share (b,t) -> pos is row-uniform.
// ---------------------------------------------------------------------------
__global__ __launch_bounds__(256) void gcn_fc1_kernel(
    const float* __restrict__ x, const float* __restrict__ adj,
    const float* __restrict__ gcn_w, const float* __restrict__ gcn_b,
    const unsigned short* __restrict__ fc1T,  // [256][256] bf16
    const float* __restrict__ fc1_b,
    const float* __restrict__ pos_em,         // chunk-offset, ld 256
    unsigned short* __restrict__ tokb, int b0) {
  int bl = blockIdx.x / T_;
  int t = blockIdx.x % T_;
  int b = b0 + bl;
  int tid = threadIdx.x;
  const int lane = tid & 63, w = tid >> 6;
  const int l15 = lane & 15, lg = lane >> 4;
  __shared__ float sX[512];               // x[b,:,t,:]  [64][8]
  __shared__ float sXA[512];              // xa          [64][8]
  __shared__ unsigned short Gs[64 * 256]; // 32 KB, granule-XOR layout
  const float* adjb = adj + b * 4096;
  for (int i = tid; i < 512; i += 256) {
    int n = i >> 3, f = i & 7;
    sX[i] = x[((long)(b * 64 + n) * T_ + t) * F_ + f];
  }
  __syncthreads();
  for (int i = tid; i < 512; i += 256) {
    int m = i >> 3, f = i & 7;
    float s = 0.f;
    for (int n = 0; n < 64; ++n) s += adjb[(m << 6) + n] * sX[(n << 3) + f];
    sXA[i] = s;
  }
  // tokb cols 0..7 = x + pos
  {
    long pbase = ((long)bl * T_ + t) * E_;
    for (int i = tid; i < 512; i += 256) {
      int m = i >> 3, f = i & 7;
      long lrow = (long)(bl * 64 + m) * T_ + t;
      tokb[lrow * E_ + f] = f2b(sX[i] + pos_em[pbase + f]);
    }
  }
  __syncthreads();
  // G -> LDS (granule-XOR layout: elem (m,d) at ((m<<5)+swg)*8 + (d&7))
  for (int i = tid; i < 64 * 256; i += 256) {
    int m = i >> 8, d = i & 255;
    float v = 0.f;
    if (d < 248) {
      float s = gcn_b[d];
      const float* xam = &sXA[m << 3];
#pragma unroll
      for (int f = 0; f < 8; ++f) s += xam[f] * gcn_w[f * 248 + d];
      v = fmaxf(s, 0.f);
    }
    int g = d >> 3;
    int swg = (g & 24) | ((g & 7) ^ (m & 7));
    Gs[((m << 5) + swg) * 8 + (d & 7)] = f2b(v);
  }

  // ---- fc1 MFMA phase (swapped operands, depth-2 weight prefetch) ----
  f32x4 acc[4][4];
#pragma unroll
  for (int i = 0; i < 4; ++i)
#pragma unroll
    for (int j = 0; j < 4; ++j) acc[i][j] = (f32x4){0.f, 0.f, 0.f, 0.f};
  const int n0w = w * 64;
  bf16x8 Wa[4], Wb[4], Xf[4];
  auto ldw = [&](bf16x8 (&W)[4], int ks) {
#pragma unroll
    for (int nf = 0; nf < 4; ++nf)
      W[nf] = *reinterpret_cast<const bf16x8*>(
          fc1T + (long)(n0w + nf * 16 + l15) * 256 + ks * 32 + (lg << 3));
  };
  auto ldx = [&](int ks) {
#pragma unroll
    for (int mf = 0; mf < 4; ++mf) {
      int row = (mf << 4) + l15;
      int ksg = (ks << 2) + lg;
      int sw = (ksg & 24) | ((ksg & 7) ^ (row & 7));
      Xf[mf] = *reinterpret_cast<const bf16x8*>(&Gs[((row << 5) + sw) * 8]);
    }
  };
  auto mm = [&](bf16x8 (&W)[4]) {
    __builtin_amdgcn_s_setprio(1);
#pragma unroll
    for (int mf = 0; mf < 4; ++mf)
#pragma unroll
      for (int nf = 0; nf < 4; ++nf)
        acc[mf][nf] = __builtin_amdgcn_mfma_f32_16x16x32_bf16(W[nf], Xf[mf], acc[mf][nf], 0, 0, 0);
    __builtin_amdgcn_s_setprio(0);
  };
  ldw(Wa, 0);
  __syncthreads();
#pragma unroll
  for (int kp = 0; kp < 4; ++kp) {
    ldw(Wb, kp * 2 + 1);
    ldx(kp * 2);
    mm(Wa);
    if (kp < 3) ldw(Wa, kp * 2 + 2);
    ldx(kp * 2 + 1);
    mm(Wb);
  }

  // ---- epilogue: tokb[:, 8+gcol] = acc + fc1_b + pos (rows strided by T) ---
  const int cb = lg << 2;
  long pbase = ((long)bl * T_ + t) * E_ + 8;
#pragma unroll
  for (int mf = 0; mf < 4; ++mf) {
    int m = (mf << 4) + l15;
    long rbase = ((long)(bl * 64 + m) * T_ + t) * E_ + 8;
#pragma unroll
    for (int nf = 0; nf < 4; ++nf) {
      int gcol = n0w + (nf << 4) + cb;
      if (gcol < 248) {
        f32x4u b4 = *reinterpret_cast<const f32x4u*>(fc1_b + gcol);
        f32x4u e4 = *reinterpret_cast<const f32x4u*>(pos_em + pbase + gcol);
        float v0 = acc[mf][nf][0] + b4[0] + e4[0];
        float v1 = acc[mf][nf][1] + b4[1] + e4[1];
        float v2 = acc[mf][nf][2] + b4[2] + e4[2];
        float v3 = acc[mf][nf][3] + b4[3] + e4[3];
        uint2 p = {cvtpk(v0, v1), cvtpk(v2, v3)};
        *reinterpret_cast<uint2*>(tokb + rbase + gcol) = p;
      }
    }
  }
}

// ---------------------------------------------------------------------------
// Residency-first MFMA GEMM, SWAPPED operands (C^T fragments), vectorized
// epilogue, weight-prefetch pipelined, setprio. BM=64, BN=WAVES*64.
// emb1 (f32) indexed [ar*lde + c0 + gcol] with ar = (row/NT)*T + row%T.
// ---------------------------------------------------------------------------
template <int KCHUNKS, int WAVES>
__global__ __launch_bounds__(WAVES * 64) void block_gemm(
    const unsigned short* __restrict__ A, int lda,
    const unsigned short* __restrict__ Bt, int K, int Nact,
    const float* __restrict__ bias,
    float* Cf, unsigned short* Cb1,
    const float* __restrict__ emb1,
    const unsigned short* __restrict__ resb, const float* resf,
    int c0, int ldc, int lde, int relu) {
  __shared__ unsigned short As[64 * 256];   // 32 KB
  const int tid = threadIdx.x;
  const int lane = tid & 63, w = tid >> 6;
  const int l15 = lane & 15, lg = lane >> 4;
  const int m0 = blockIdx.x * 64;
  const int n0w = blockIdx.y * (WAVES * 64) + w * 64;

  f32x4 acc[4][4];
#pragma unroll
  for (int i = 0; i < 4; ++i)
#pragma unroll
    for (int j = 0; j < 4; ++j) acc[i][j] = (f32x4){0.f, 0.f, 0.f, 0.f};

  for (int kc = 0; kc < KCHUNKS; ++kc) {
    if (kc) __syncthreads();
    // whole-wave-guarded staging (2048 granules; stride multiple of 64)
    for (int base = 0; base < 2048; base += WAVES * 64) {
      int idx = base + tid;
      if (idx < 2048) {
        int row = idx >> 5, g = idx & 31;
        int swg = (g & 24) | ((g & 7) ^ (row & 7));
        gload16(A + (long)(m0 + row) * lda + kc * 256 + swg * 8,
                &As[(base + w * 64) * 8]);
      }
    }
    bf16x8 Wa[4], Wb[4], Xf[4];
    auto ldw = [&](bf16x8 (&W)[4], int ks) {
#pragma unroll
      for (int nf = 0; nf < 4; ++nf)
        W[nf] = *reinterpret_cast<const bf16x8*>(
            Bt + (long)(n0w + nf * 16 + l15) * K + kc * 256 + ks * 32 + (lg << 3));
    };
    auto ldx = [&](int ks) {
#pragma unroll
      for (int mf = 0; mf < 4; ++mf) {
        int row = (mf << 4) + l15;
        int ksg = (ks << 2) + lg;
        int sw = (ksg & 24) | ((ksg & 7) ^ (row & 7));
        Xf[mf] = *reinterpret_cast<const bf16x8*>(&As[((row << 5) + sw) * 8]);
      }
    };
    auto mm = [&](bf16x8 (&W)[4]) {
      __builtin_amdgcn_s_setprio(1);
#pragma unroll
      for (int mf = 0; mf < 4; ++mf)
#pragma unroll
        for (int nf = 0; nf < 4; ++nf)
          acc[mf][nf] = __builtin_amdgcn_mfma_f32_16x16x32_bf16(W[nf], Xf[mf], acc[mf][nf], 0, 0, 0);
      __builtin_amdgcn_s_setprio(0);
    };
    ldw(Wa, 0);                       // overlaps the staging drain below
    asm volatile("s_waitcnt vmcnt(0)" ::: "memory");
    __syncthreads();
#pragma unroll
    for (int kp = 0; kp < 4; ++kp) {
      ldw(Wb, kp * 2 + 1);
      ldx(kp * 2);
      mm(Wa);
      if (kp < 3) ldw(Wa, kp * 2 + 2);
      ldx(kp * 2 + 1);
      mm(Wb);
    }
  }

  const int cb = lg << 2;
#pragma unroll
  for (int mf = 0; mf < 4; ++mf) {
    int rr = m0 + (mf << 4) + l15;
    int ar = (rr / NT_) * T_ + (rr % T_);
    long rbase  = (long)rr * ldc + c0;
    long rbase2 = (long)rr * 256 + c0;
    long abase  = (long)ar * lde + c0;
#pragma unroll
    for (int nf = 0; nf < 4; ++nf) {
      int gcol = n0w + (nf << 4) + cb;
      if (gcol < Nact) {
        float v0 = acc[mf][nf][0], v1 = acc[mf][nf][1];
        float v2 = acc[mf][nf][2], v3 = acc[mf][nf][3];
        if (bias) {
          f32x4u b4 = *reinterpret_cast<const f32x4u*>(bias + gcol);
          v0 += b4[0]; v1 += b4[1]; v2 += b4[2]; v3 += b4[3];
        }
        if (relu) {
          v0 = fmaxf(v0, 0.f); v1 = fmaxf(v1, 0.f);
          v2 = fmaxf(v2, 0.f); v3 = fmaxf(v3, 0.f);
        }
        if (resb) {
          ushort4 rv = *reinterpret_cast<const ushort4*>(resb + rbase2 + gcol);
          v0 += b2f(rv.x); v1 += b2f(rv.y); v2 += b2f(rv.z); v3 += b2f(rv.w);
        }
        if (resf) {
          f32x4u r4 = *reinterpret_cast<const f32x4u*>(resf + rbase + gcol);
          v0 += r4[0]; v1 += r4[1]; v2 += r4[2]; v3 += r4[3];
        }
        if (emb1) {
          f32x4u e4 = *reinterpret_cast<const f32x4u*>(emb1 + abase + gcol);
          v0 += e4[0]; v1 += e4[1]; v2 += e4[2]; v3 += e4[3];
        }
        if (Cf) {
          f32x4u o; o[0] = v0; o[1] = v1; o[2] = v2; o[3] = v3;
          *reinterpret_cast<f32x4u*>(Cf + rbase + gcol) = o;
        }
        if (Cb1) {
          uint2 p = {cvtpk(v0, v1), cvtpk(v2, v3)};
          *reinterpret_cast<uint2*>(Cb1 + rbase + gcol) = p;
        }
      }
    }
  }
}

// ---------------------------------------------------------------------------
// wo GEMM + residual + LayerNorm1 fused: h1b = LN(tok + O @ wo + bo).
// BM=64, BN=256, K=256, weight-prefetch pipelined, setprio.
// ---------------------------------------------------------------------------
__global__ __launch_bounds__(256) void wo_ln_kernel(
    const unsigned short* __restrict__ A, int lda,     // O (qkv slice)
    const unsigned short* __restrict__ Wt,             // woT [256][256]
    const float* __restrict__ bias,                    // bo
    const unsigned short* __restrict__ resb,           // tokb (ld 256)
    const float* __restrict__ lng, const float* __restrict__ lnb,
    unsigned short* __restrict__ outb) {               // h1b (may alias resb)
  __shared__ unsigned short As[64 * 256];   // 32 KB
  __shared__ float red[4][4][16][2];        // 2 KB
  const int tid = threadIdx.x;
  const int lane = tid & 63, w = tid >> 6;
  const int l15 = lane & 15, lg = lane >> 4;
  const int m0 = blockIdx.x * 64;
  const int n0w = w * 64;

  f32x4 acc[4][4];
#pragma unroll
  for (int i = 0; i < 4; ++i)
#pragma unroll
    for (int j = 0; j < 4; ++j) acc[i][j] = (f32x4){0.f, 0.f, 0.f, 0.f};

#pragma unroll
  for (int j = 0; j < 8; ++j) {
    int idx = j * 256 + tid;
    int row = idx >> 5, g = idx & 31;
    int swg = (g & 24) | ((g & 7) ^ (row & 7));
    gload16(A + (long)(m0 + row) * lda + swg * 8, &As[(j * 256 + w * 64) * 8]);
  }
  bf16x8 Wa[4], Wb[4], Xf[4];
  auto ldw = [&](bf16x8 (&W)[4], int ks) {
#pragma unroll
    for (int nf = 0; nf < 4; ++nf)
      W[nf] = *reinterpret_cast<const bf16x8*>(
          Wt + (long)(n0w + nf * 16 + l15) * 256 + ks * 32 + (lg << 3));
  };
  auto ldx = [&](int ks) {
#pragma unroll
    for (int mf = 0; mf < 4; ++mf) {
      int row = (mf << 4) + l15;
      int ksg = (ks << 2) + lg;
      int sw = (ksg & 24) | ((ksg & 7) ^ (row & 7));
      Xf[mf] = *reinterpret_cast<const bf16x8*>(&As[((row << 5) + sw) * 8]);
    }
  };
  auto mm = [&](bf16x8 (&W)[4]) {
    __builtin_amdgcn_s_setprio(1);
#pragma unroll
    for (int mf = 0; mf < 4; ++mf)
#pragma unroll
      for (int nf = 0; nf < 4; ++nf)
        acc[mf][nf] = __builtin_amdgcn_mfma_f32_16x16x32_bf16(W[nf], Xf[mf], acc[mf][nf], 0, 0, 0);
    __builtin_amdgcn_s_setprio(0);
  };
  ldw(Wa, 0);
  asm volatile("s_waitcnt vmcnt(0)" ::: "memory");
  __syncthreads();
#pragma unroll
  for (int kp = 0; kp < 4; ++kp) {
    ldw(Wb, kp * 2 + 1);
    ldx(kp * 2);
    mm(Wa);
    if (kp < 3) ldw(Wa, kp * 2 + 2);
    ldx(kp * 2 + 1);
    mm(Wb);
  }

  // ---- epilogue: v = acc + bo + tok ; row stats ; LN ; bf16 store ----
  const int cb = lg << 2;
  float s[4], s2[4];
#pragma unroll
  for (int mf = 0; mf < 4; ++mf) {
    int rr = m0 + (mf << 4) + l15;
    long rbase2 = (long)rr * 256;
    s[mf] = 0.f; s2[mf] = 0.f;
#pragma unroll
    for (int nf = 0; nf < 4; ++nf) {
      int gcol = n0w + (nf << 4) + cb;
      f32x4u b4 = *reinterpret_cast<const f32x4u*>(bias + gcol);
      ushort4 rv = *reinterpret_cast<const ushort4*>(resb + rbase2 + gcol);
      float v0 = acc[mf][nf][0] + b4[0] + b2f(rv.x);
      float v1 = acc[mf][nf][1] + b4[1] + b2f(rv.y);
      float v2 = acc[mf][nf][2] + b4[2] + b2f(rv.z);
      float v3 = acc[mf][nf][3] + b4[3] + b2f(rv.w);
      acc[mf][nf][0] = v0; acc[mf][nf][1] = v1;
      acc[mf][nf][2] = v2; acc[mf][nf][3] = v3;
      s[mf] += v0 + v1 + v2 + v3;
      s2[mf] += v0 * v0 + v1 * v1 + v2 * v2 + v3 * v3;
    }
    s[mf] += __shfl_xor(s[mf], 16, 64);
    s[mf] += __shfl_xor(s[mf], 32, 64);
    s2[mf] += __shfl_xor(s2[mf], 16, 64);
    s2[mf] += __shfl_xor(s2[mf], 32, 64);
    if (lg == 0) { red[w][mf][l15][0] = s[mf]; red[w][mf][l15][1] = s2[mf]; }
  }
  __syncthreads();
#pragma unroll
  for (int mf = 0; mf < 4; ++mf) {
    float S  = red[0][mf][l15][0] + red[1][mf][l15][0] + red[2][mf][l15][0] + red[3][mf][l15][0];
    float S2 = red[0][mf][l15][1] + red[1][mf][l15][1] + red[2][mf][l15][1] + red[3][mf][l15][1];
    float mean = S * 0.00390625f;
    float var = S2 * 0.00390625f - mean * mean;
    float rs = rsqrtf(var + 1e-5f);
    int rr = m0 + (mf << 4) + l15;
    long rbase = (long)rr * 256;
#pragma unroll
    for (int nf = 0; nf < 4; ++nf) {
      int gcol = n0w + (nf << 4) + cb;
      f32x4u g4 = *reinterpret_cast<const f32x4u*>(lng + gcol);
      f32x4u t4 = *reinterpret_cast<const f32x4u*>(lnb + gcol);
      float o0 = (acc[mf][nf][0] - mean) * rs * g4[0] + t4[0];
      float o1 = (acc[mf][nf][1] - mean) * rs * g4[1] + t4[1];
      float o2 = (acc[mf][nf][2] - mean) * rs * g4[2] + t4[2];
      float o3 = (acc[mf][nf][3] - mean) * rs * g4[3] + t4[3];
      uint2 p = {cvtpk(o0, o1), cvtpk(o2, o3)};
      *reinterpret_cast<uint2*>(outb + rbase + gcol) = p;
    }
  }
}

// ---------------------------------------------------------------------------
// FUSED FF + LN2 (measured-best r15 variant): 512 threads (8 waves), 52KB LDS,
// stage-1 nf=1 depth-2 weight prefetch, stage-2 nf=2 depth-2, single fis,
// two barriers per half-chunk.
// ---------------------------------------------------------------------------
__global__ __launch_bounds__(512, 4) void ff_fused_kernel(
    const unsigned short* __restrict__ h1,   // [rows][256] bf16
    const unsigned short* __restrict__ W1,   // ff1T [1024][256]
    const unsigned short* __restrict__ W2,   // ff2T [256][1024]
    const float* __restrict__ b1, const float* __restrict__ b2,
    const float* __restrict__ lng, const float* __restrict__ lnb,
    float* __restrict__ out) {               // f32 [rows][256]
  __shared__ unsigned short h1s[64 * 256];   // 32 KB
  __shared__ unsigned short fis[64 * 128];   // 16 KB (128-col half-chunk)
  __shared__ float red[8][4][16][2];         // 4 KB
  const int tid = threadIdx.x;
  const int lane = tid & 63, w = tid >> 6;   // 8 waves
  const int l15 = lane & 15, lg = lane >> 4;
  const int m0 = blockIdx.x * 64;

  // ---- stage h1 strip (source-side XOR swizzle), 4 iters @ 512 thr ----
#pragma unroll
  for (int j = 0; j < 4; ++j) {
    int idx = j * 512 + tid;
    int row = idx >> 5, g = idx & 31;
    int swg = (g & 24) | ((g & 7) ^ (row & 7));
    gload16(h1 + (long)(m0 + row) * 256 + swg * 8, &h1s[(j * 512 + w * 64) * 8]);
  }

  f32x4 acc2[4][2];
#pragma unroll
  for (int i = 0; i < 4; ++i)
#pragma unroll
    for (int j = 0; j < 2; ++j) acc2[i][j] = (f32x4){0.f, 0.f, 0.f, 0.f};

  bf16x8 W1a, W1b, W2a[2], W2b[2], Xf[4];
  auto ldw1 = [&](bf16x8& W, int hc, int ks) {
    W = *reinterpret_cast<const bf16x8*>(
        W1 + (long)(hc * 128 + w * 16 + l15) * 256 + ks * 32 + (lg << 3));
  };
  auto ldw2 = [&](bf16x8 (&W)[2], int hc, int ks) {
#pragma unroll
    for (int nf = 0; nf < 2; ++nf)
      W[nf] = *reinterpret_cast<const bf16x8*>(
          W2 + (long)(w * 32 + nf * 16 + l15) * 1024 + hc * 128 + ks * 32 + (lg << 3));
  };
  auto ldxh = [&](int ks) {   // from h1s (32 granules/row)
#pragma unroll
    for (int mf = 0; mf < 4; ++mf) {
      int row = (mf << 4) + l15;
      int ksg = (ks << 2) + lg;
      int sw = (ksg & 24) | ((ksg & 7) ^ (row & 7));
      Xf[mf] = *reinterpret_cast<const bf16x8*>(&h1s[((row << 5) + sw) * 8]);
    }
  };
  auto ldxf = [&](int ks) {   // from fis (16 granules/row, k=128)
#pragma unroll
    for (int mf = 0; mf < 4; ++mf) {
      int row = (mf << 4) + l15;
      int ksg = (ks << 2) + lg;
      int sw = (ksg & 8) | ((ksg & 7) ^ (row & 7));
      Xf[mf] = *reinterpret_cast<const bf16x8*>(&fis[((row << 4) + sw) * 8]);
    }
  };

  const int cb = lg << 2;
  bool first = true;
  for (int hc = 0; hc < 8; ++hc) {
    // ---- stage 1: acc1 = h1 @ ff1[:, hc*128 + w*16 .. +15] (pipelined) ----
    f32x4 acc1[4];
#pragma unroll
    for (int i = 0; i < 4; ++i) acc1[i] = (f32x4){0.f, 0.f, 0.f, 0.f};
    ldw1(W1a, hc, 0);
    if (first) {
      asm volatile("s_waitcnt vmcnt(1)" ::: "memory");  // h1s staged (W1a in flight)
      __syncthreads();
      first = false;
    }
#pragma unroll
    for (int kp = 0; kp < 4; ++kp) {
      ldw1(W1b, hc, kp * 2 + 1);
      ldxh(kp * 2);
      __builtin_amdgcn_s_setprio(1);
#pragma unroll
      for (int mf = 0; mf < 4; ++mf)
        acc1[mf] = __builtin_amdgcn_mfma_f32_16x16x32_bf16(W1a, Xf[mf], acc1[mf], 0, 0, 0);
      __builtin_amdgcn_s_setprio(0);
      if (kp < 3) ldw1(W1a, hc, kp * 2 + 2);
      ldxh(kp * 2 + 1);
      __builtin_amdgcn_s_setprio(1);
#pragma unroll
      for (int mf = 0; mf < 4; ++mf)
        acc1[mf] = __builtin_amdgcn_mfma_f32_16x16x32_bf16(W1b, Xf[mf], acc1[mf], 0, 0, 0);
      __builtin_amdgcn_s_setprio(0);
    }
    if (hc) __syncthreads();   // prior stage-2 reads of fis done
    // relu + bias -> bf16 -> fis (granule-XOR, half-chunk local cols 0..127)
#pragma unroll
    for (int mf = 0; mf < 4; ++mf) {
      int row = (mf << 4) + l15;
      int col = w * 16 + cb;               // 0..127 within half-chunk
      f32x4u b4 = *reinterpret_cast<const f32x4u*>(b1 + hc * 128 + col);
      float v0 = fmaxf(acc1[mf][0] + b4[0], 0.f);
      float v1 = fmaxf(acc1[mf][1] + b4[1], 0.f);
      float v2 = fmaxf(acc1[mf][2] + b4[2], 0.f);
      float v3 = fmaxf(acc1[mf][3] + b4[3], 0.f);
      int g = col >> 3;                    // 0..15
      int swg = (g & 8) | ((g & 7) ^ (row & 7));
      uint2 p = {cvtpk(v0, v1), cvtpk(v2, v3)};
      *reinterpret_cast<uint2*>(&fis[((row << 4) + swg) * 8 + (col & 7)]) = p;
    }
    ldw2(W2a, hc, 0);          // prefetch stage-2 weights during barrier
    __syncthreads();
    // ---- stage 2: acc2 += fis_half @ ff2[hc*128.., :] (4 ks, pipelined) ----
#pragma unroll
    for (int kp = 0; kp < 2; ++kp) {
      ldw2(W2b, hc, kp * 2 + 1);
      ldxf(kp * 2);
      __builtin_amdgcn_s_setprio(1);
#pragma unroll
      for (int mf = 0; mf < 4; ++mf)
#pragma unroll
        for (int nf = 0; nf < 2; ++nf)
          acc2[mf][nf] = __builtin_amdgcn_mfma_f32_16x16x32_bf16(W2a[nf], Xf[mf], acc2[mf][nf], 0, 0, 0);
      __builtin_amdgcn_s_setprio(0);
      if (kp < 1) ldw2(W2a, hc, kp * 2 + 2);
      ldxf(kp * 2 + 1);
      __builtin_amdgcn_s_setprio(1);
#pragma unroll
      for (int mf = 0; mf < 4; ++mf)
#pragma unroll
        for (int nf = 0; nf < 2; ++nf)
          acc2[mf][nf] = __builtin_amdgcn_mfma_f32_16x16x32_bf16(W2b[nf], Xf[mf], acc2[mf][nf], 0, 0, 0);
      __builtin_amdgcn_s_setprio(0);
    }
  }

  // ---- epilogue: v = acc2 + b2 + h1 ; LN2 ; f32 store ----
  float s[4], s2[4];
#pragma unroll
  for (int mf = 0; mf < 4; ++mf) {
    int row = (mf << 4) + l15;
    s[mf] = 0.f; s2[mf] = 0.f;
#pragma unroll
    for (int nf = 0; nf < 2; ++nf) {
      int gcol = w * 32 + (nf << 4) + cb;
      f32x4u b4 = *reinterpret_cast<const f32x4u*>(b2 + gcol);
      int g = gcol >> 3;
      int swg = (g & 24) | ((g & 7) ^ (row & 7));
      ushort4 rv = *reinterpret_cast<const ushort4*>(&h1s[((row << 5) + swg) * 8 + (gcol & 7)]);
      float v0 = acc2[mf][nf][0] + b4[0] + b2f(rv.x);
      float v1 = acc2[mf][nf][1] + b4[1] + b2f(rv.y);
      float v2 = acc2[mf][nf][2] + b4[2] + b2f(rv.z);
      float v3 = acc2[mf][nf][3] + b4[3] + b2f(rv.w);
      acc2[mf][nf][0] = v0; acc2[mf][nf][1] = v1;
      acc2[mf][nf][2] = v2; acc2[mf][nf][3] = v3;
      s[mf] += v0 + v1 + v2 + v3;
      s2[mf] += v0 * v0 + v1 * v1 + v2 * v2 + v3 * v3;
    }
    s[mf] += __shfl_xor(s[mf], 16, 64);
    s[mf] += __shfl_xor(s[mf], 32, 64);
    s2[mf] += __shfl_xor(s2[mf], 16, 64);
    s2[mf] += __shfl_xor(s2[mf], 32, 64);
    if (lg == 0) { red[w][mf][l15][0] = s[mf]; red[w][mf][l15][1] = s2[mf]; }
  }
  __syncthreads();
#pragma unroll
  for (int mf = 0; mf < 4; ++mf) {
    float S = 0.f, S2 = 0.f;
#pragma unroll
    for (int ww = 0; ww < 8; ++ww) { S += red[ww][mf][l15][0]; S2 += red[ww][mf][l15][1]; }
    float mean = S * 0.00390625f;
    float var = S2 * 0.00390625f - mean * mean;
    float rs = rsqrtf(var + 1e-5f);
    int rr = m0 + (mf << 4) + l15;
    long rbase = (long)rr * 256;
#pragma unroll
    for (int nf = 0; nf < 2; ++nf) {
      int gcol = w * 32 + (nf << 4) + cb;
      f32x4u g4 = *reinterpret_cast<const f32x4u*>(lng + gcol);
      f32x4u t4 = *reinterpret_cast<const f32x4u*>(lnb + gcol);
      f32x4u o;
      o[0] = (acc2[mf][nf][0] - mean) * rs * g4[0] + t4[0];
      o[1] = (acc2[mf][nf][1] - mean) * rs * g4[1] + t4[1];
      o[2] = (acc2[mf][nf][2] - mean) * rs * g4[2] + t4[2];
      o[3] = (acc2[mf][nf][3] - mean) * rs * g4[3] + t4[3];
      *reinterpret_cast<f32x4u*>(out + rbase + gcol) = o;
    }
  }
}

// ---------------------------------------------------------------------------
// MFMA attention: one block (4 waves) per (bn, h), QKV interleaved ld=LDQ_.
// ---------------------------------------------------------------------------
__global__ __launch_bounds__(256) void attn_mfma_kernel(unsigned short* QKV) {
  int blk = blockIdx.x;
  int bn = blk >> 3, h = blk & 7;
  int tid = threadIdx.x;
  int lane = tid & 63, w = tid >> 6;

  __shared__ unsigned short Kfr[11 * 512];    // fragment-linear K tiles
  __shared__ unsigned short VT[32][200];      // V^T (dh x key), pad
  __shared__ unsigned short Pb[4][16][200];   // per-wave P buffers

  const long qbase = (long)bn * T_ * LDQ_ + h * DH_;
  const unsigned short* Kg = QKV + qbase + 256;
  const unsigned short* V  = QKV + qbase + 512;
  const unsigned short* Q  = QKV + qbase;
  unsigned short* O = QKV + qbase;
  int l15 = lane & 15, lg = lane >> 4;

  for (int kt = w; kt < 11; kt += 4) {
    gload16(Kg + (long)(kt * 16 + l15) * LDQ_ + (lg << 3), &Kfr[kt * 512]);
  }
  for (int i = tid; i < T_ * 4; i += 256) {
    int t = i >> 2, seg = (i & 3) << 3;
    uint4 vv = *reinterpret_cast<const uint4*>(V + (long)t * LDQ_ + seg);
    const unsigned short* vs = (const unsigned short*)&vv;
#pragma unroll
    for (int j = 0; j < 8; ++j) VT[seg + j][t] = vs[j];
  }
  for (int i = tid; i < 32 * 32; i += 256) VT[i >> 5][168 + (i & 31)] = 0;
  {
    unsigned short* pflat = &Pb[0][0][0];
    for (int i = tid; i < 64 * 24; i += 256)
      pflat[(i / 24) * 200 + 176 + (i % 24)] = 0;
  }
  __syncthreads();

  const float scale = 0.17677669529663687f;  // 1/sqrt(32)
  unsigned short* Pw = &Pb[w][0][0];

  for (int it = 0; it < 3; ++it) {
    int qt = w + it * 4;
    if (qt > 10) break;
    bf16x8 af = *reinterpret_cast<const bf16x8*>(
        Q + (long)(qt * 16 + l15) * LDQ_ + (lg << 3));
    f32x4 s[11];
#pragma unroll
    for (int kt = 0; kt < 11; ++kt) {
      bf16x8 bf = *reinterpret_cast<const bf16x8*>(&Kfr[kt * 512 + lane * 8]);
      s[kt] = __builtin_amdgcn_mfma_f32_16x16x32_bf16(
          af, bf, (f32x4){0.f, 0.f, 0.f, 0.f}, 0, 0, 0);
    }
    bool ok10 = (l15 < 8);
    float inv_l[4];
#pragma unroll
    for (int r = 0; r < 4; ++r) {
      float mx = -1e30f;
#pragma unroll
      for (int kt = 0; kt < 10; ++kt) mx = fmaxf(mx, s[kt][r] * scale);
      if (ok10) mx = fmaxf(mx, s[10][r] * scale);
#pragma unroll
      for (int off = 1; off < 16; off <<= 1) mx = fmaxf(mx, __shfl_xor(mx, off, 64));
      float pv[11];
      float ls = 0.f;
#pragma unroll
      for (int kt = 0; kt < 11; ++kt) {
        bool valid = (kt < 10) || ok10;
        float p = valid ? __expf(s[kt][r] * scale - mx) : 0.f;
        pv[kt] = p;
        ls += p;
      }
#pragma unroll
      for (int off = 1; off < 16; off <<= 1) ls += __shfl_xor(ls, off, 64);
      inv_l[r] = 1.f / ls;
      int prow = (lg << 2) + r;
#pragma unroll
      for (int kt = 0; kt < 11; ++kt)
        Pw[prow * 200 + kt * 16 + l15] = f2b(pv[kt]);
    }
    asm volatile("s_waitcnt lgkmcnt(0)" ::: "memory");
    __builtin_amdgcn_sched_barrier(0);
    f32x4 o0 = (f32x4){0.f, 0.f, 0.f, 0.f};
    f32x4 o1 = (f32x4){0.f, 0.f, 0.f, 0.f};
#pragma unroll
    for (int ks = 0; ks < 6; ++ks) {
      bf16x8 pf = *reinterpret_cast<const bf16x8*>(&Pw[l15 * 200 + ks * 32 + (lg << 3)]);
      bf16x8 v0 = *reinterpret_cast<const bf16x8*>(&VT[l15][ks * 32 + (lg << 3)]);
      bf16x8 v1 = *reinterpret_cast<const bf16x8*>(&VT[16 + l15][ks * 32 + (lg << 3)]);
      o0 = __builtin_amdgcn_mfma_f32_16x16x32_bf16(pf, v0, o0, 0, 0, 0);
      o1 = __builtin_amdgcn_mfma_f32_16x16x32_bf16(pf, v1, o1, 0, 0, 0);
    }
    int rg = lg << 2;
#pragma unroll
    for (int r = 0; r < 4; ++r) {
      int q = qt * 16 + rg + r;
      if (q < T_) {
        long ob = (long)q * LDQ_;
        O[ob + l15]      = f2b(o0[r] * inv_l[r]);
        O[ob + 16 + l15] = f2b(o1[r] * inv_l[r]);
      }
    }
  }
}

// ---------------------------------------------------------------------------
extern "C" void kernel_launch(void* const* d_in, const int* in_sizes, int n_in,
                              void* d_out, int out_size, void* d_ws, size_t ws_size,
                              hipStream_t stream) {
  const float* x      = (const float*)d_in[0];
  const float* locs   = (const float*)d_in[1];
  const float* pos_em = (const float*)d_in[2];
  const float* per_em = (const float*)d_in[3];
  const float* gcn_w  = (const float*)d_in[4];
  const float* gcn_b  = (const float*)d_in[5];
  const float* fc1_w  = (const float*)d_in[6];
  const float* fc1_b  = (const float*)d_in[7];
  const float* wq = (const float*)d_in[8];
  const float* bq = (const float*)d_in[9];
  const float* wk = (const float*)d_in[10];
  const float* bk = (const float*)d_in[11];
  const float* wv = (const float*)d_in[12];
  const float* bv = (const float*)d_in[13];
  const float* wo = (const float*)d_in[14];
  const float* bo = (const float*)d_in[15];
  const float* ln1_g = (const float*)d_in[16];
  const float* ln1_b = (const float*)d_in[17];
  const float* ln2_g = (const float*)d_in[18];
  const float* ln2_b = (const float*)d_in[19];
  const float* ff1_w = (const float*)d_in[20];
  const float* ff1_b = (const float*)d_in[21];
  const float* ff2_w = (const float*)d_in[22];
  const float* ff2_b = (const float*)d_in[23];
  float* out = (float*)d_out;

  // ---- workspace layout ---------------------------------------------------
  const size_t ADJ_BYTES = 1u << 20;
  const size_t WB_BYTES  = 16u << 20;   // weights + perb + perqv
  int CB = 16;
  while (CB > 1) {
    if (ADJ_BYTES + WB_BYTES + (size_t)CB * NT_ * 2048 <= ws_size) break;
    CB >>= 1;
  }
  char* ws = (char*)d_ws;
  float* adj = (float*)ws;
  unsigned short* wslab = (unsigned short*)(ws + ADJ_BYTES);
  unsigned short* fc1T   = wslab;                        // [256][256]
  unsigned short* wqkvT  = wslab + 65536;                // [768][256] (wq|wk|wv)
  unsigned short* woT    = wslab + 65536 + 196608;       // [256][256]
  unsigned short* ff1T   = wslab + 65536 + 196608 + 65536;          // [1024][256]
  unsigned short* ff2T   = wslab + 65536 + 196608 + 65536 + 262144; // [256][1024]
  float* bqk = (float*)(ws + ADJ_BYTES + 1900544);       // [512] concat bias
  unsigned short* perb = (unsigned short*)(ws + ADJ_BYTES + (2u << 20));  // [2688][256] bf16
  float* perqv = (float*)(ws + ADJ_BYTES + (4u << 20));                   // [2688][768] f32

  unsigned short* tokb = (unsigned short*)(ws + ADJ_BYTES + WB_BYTES);
  unsigned short* qkv  = tokb + (size_t)CB * NT_ * 256; // [rows][768] Q|K|V
  unsigned short* h1b  = tokb;                          // bf16 h1 (over tokb)

  adj_kernel<<<B_, 64, 0, stream>>>(locs, adj);
  convw_kernel<<<256, 256, 0, stream>>>(fc1_w, fc1T, 248, 248, 256, 256);
  convw_kernel<<<256, 256, 0, stream>>>(wq, wqkvT, 256, 256, 256, 256);
  convw_kernel<<<256, 256, 0, stream>>>(wk, wqkvT + 65536, 256, 256, 256, 256);
  convw_kernel<<<256, 256, 0, stream>>>(wv, wqkvT + 2 * 65536, 256, 256, 256, 256);
  convw_kernel<<<256, 256, 0, stream>>>(wo, woT, 256, 256, 256, 256);
  convw_kernel<<<1024, 256, 0, stream>>>(ff1_w, ff1T, 256, 1024, 256, 1024);
  convw_kernel<<<1024, 256, 0, stream>>>(ff2_w, ff2T, 1024, 256, 1024, 256);
  cvtb_kernel<<<BT_, 256, 0, stream>>>(per_em, perb, BT_ * 256);
  hipMemcpyAsync(bqk, bq, 256 * sizeof(float), hipMemcpyDeviceToDevice, stream);
  hipMemcpyAsync(bqk + 256, bk, 256 * sizeof(float), hipMemcpyDeviceToDevice, stream);
  // perqv[:, 0:512] = per_em @ (wq|wk) + bqk  (f32, ldc=768)
  block_gemm<1, 8><<<dim3(BT_ / 64, 1), 512, 0, stream>>>(
      perb, 256, wqkvT, 256, 512, bqk, perqv, nullptr, nullptr,
      nullptr, nullptr, 0, 768, 256, 0);
  // perqv[:, 512:768] = bv
  bvfill_kernel<<<BT_, 256, 0, stream>>>(bv, perqv);

  for (int b0 = 0; b0 < B_; b0 += CB) {
    const int rows = CB * NT_;        // multiple of 64
    const int GX = rows / 64;         // 64-row blocks
    const float* pos_c = pos_em + (long)b0 * T_ * E_;
    const float* perqv_c = perqv + (long)b0 * T_ * 768;
    float* out_c = out + (long)b0 * NT_ * E_;

    // fused GCN + fc1 -> tokb (cols 0..7 = x+pos, cols 8..255 = G@fc1+b+pos)
    gcn_fc1_kernel<<<CB * T_, 256, 0, stream>>>(x, adj, gcn_w, gcn_b,
                                                fc1T, fc1_b, pos_c, tokb, b0);
    // fused Q|K|V (N=768) from tokb -> qkv; perqv adds per-term+biases
    block_gemm<1, 12><<<dim3(GX, 1), 768, 0, stream>>>(
        tokb, 256, wqkvT, 256, 768, nullptr, nullptr, qkv, perqv_c,
        nullptr, nullptr, 0, LDQ_, 768, 0);
    // attention (O in-place over Q slice of qkv)
    attn_mfma_kernel<<<CB * N_ * H_, 256, 0, stream>>>(qkv);
    // wo + residual + LN1 fused: h1b = LN(tokb + O@wo + bo)
    wo_ln_kernel<<<GX, 256, 0, stream>>>(qkv, LDQ_, woT, bo, tokb,
                                         ln1_g, ln1_b, h1b);
    // FUSED FF + LN2: out_c = LN2(h1 + relu(h1@ff1+b1)@ff2 + b2), 8-wave
    ff_fused_kernel<<<GX, 512, 0, stream>>>(h1b, ff1T, ff2T, ff1_b, ff2_b,
                                            ln2_g, ln2_b, out_c);
  }
}

// Round 23
// 1094.128 us; speedup vs baseline: 1.0095x; 1.0095x over previous
//
#include <hip/hip_runtime.h>
#include <hip/hip_bf16.h>

// Problem dims
constexpr int B_  = 16;
constexpr int N_  = 64;     // stations
constexpr int T_  = 168;    // seq
constexpr int F_  = 8;      // raw features
constexpr int E_  = 256;    // dmodel
constexpr int H_  = 8;      // heads
constexpr int DH_ = 32;     // head dim
constexpr int NT_ = N_ * T_;           // 10752 (rows per batch)
constexpr int LDQ_ = 768;              // interleaved Q|K|V row stride
constexpr int BT_ = B_ * T_;           // 2688 embedding rows

typedef __bf16 bf16x8 __attribute__((ext_vector_type(8)));
typedef float  f32x4  __attribute__((ext_vector_type(4)));
typedef float  f32x4u __attribute__((ext_vector_type(4), aligned(4)));

__device__ __forceinline__ unsigned short f2b(float f) {
  union { float f; unsigned int u; } v; v.f = f;
  unsigned int r = (v.u + 0x7FFFu + ((v.u >> 16) & 1u)) >> 16;
  return (unsigned short)r;
}
__device__ __forceinline__ float b2f(unsigned short h) {
  union { unsigned int u; float f; } v; v.u = ((unsigned int)h) << 16;
  return v.f;
}
__device__ __forceinline__ unsigned int cvtpk(float lo, float hi) {
  unsigned int r;
  asm("v_cvt_pk_bf16_f32 %0, %1, %2" : "=v"(r) : "v"(lo), "v"(hi));
  return r;
}
__device__ __forceinline__ void gload16(const void* g, void* l) {
  __builtin_amdgcn_global_load_lds(
      (const __attribute__((address_space(1))) unsigned int*)g,
      (__attribute__((address_space(3))) unsigned int*)l, 16, 0, 0);
}

// ---------------------------------------------------------------------------
// adjacency  a[b][m][n] = 0.5*(w_norm[m][n] + (m==n))
// ---------------------------------------------------------------------------
__global__ void adj_kernel(const float* __restrict__ locs, float* __restrict__ a) {
  int b = blockIdx.x;
  int m = threadIdx.x;  // 64 threads
  __shared__ float lx[64], ly[64];
  lx[m] = locs[(b * 64 + m) * 2 + 0];
  ly[m] = locs[(b * 64 + m) * 2 + 1];
  __syncthreads();
  float x = lx[m], y = ly[m];
  float sum = 0.f;
  for (int n = 0; n < 64; ++n) {
    float dx = x - lx[n], dy = y - ly[n];
    float d = sqrtf(dx * dx + dy * dy + 1e-12f);
    sum += (n == m) ? 0.f : 1.f / d;
  }
  float inv = 0.5f / sum;
  for (int n = 0; n < 64; ++n) {
    float dx = x - lx[n], dy = y - ly[n];
    float d = sqrtf(dx * dx + dy * dy + 1e-12f);
    float w = (n == m) ? 0.5f : inv / d;
    a[(b * 64 + m) * 64 + n] = w;
  }
}

// ---------------------------------------------------------------------------
// weight convert: in f32 [K][N] (ld N) -> outT bf16 [Np][Kp] (ld Kp), zero pad
// ---------------------------------------------------------------------------
__global__ void convw_kernel(const float* __restrict__ in, unsigned short* __restrict__ outT,
                             int K, int N, int Kp, int Np) {
  int idx = blockIdx.x * 256 + threadIdx.x;
  if (idx >= Np * Kp) return;
  int n = idx / Kp, k = idx % Kp;
  float v = (k < K && n < N) ? in[(long)k * N + n] : 0.f;
  outT[idx] = f2b(v);
}

// ---------------------------------------------------------------------------
// elementwise f32 -> bf16
// ---------------------------------------------------------------------------
__global__ void cvtb_kernel(const float* __restrict__ in, unsigned short* __restrict__ out,
                            int n) {
  int i = blockIdx.x * 256 + threadIdx.x;
  if (i < n) out[i] = f2b(in[i]);
}

// ---------------------------------------------------------------------------
// GCN front-end for one (b,t) in chunk [b0, b0+CB)
// ---------------------------------------------------------------------------
__global__ __launch_bounds__(256) void gcn_kernel(
    const float* __restrict__ x, const float* __restrict__ adj,
    const float* __restrict__ gcn_w, const float* __restrict__ gcn_b,
    const float* __restrict__ pos_em,
    unsigned short* __restrict__ G, unsigned short* __restrict__ tokb, int b0) {
  int bl = blockIdx.x / T_;
  int t = blockIdx.x % T_;
  int b = b0 + bl;
  int tid = threadIdx.x;
  __shared__ float sX[512];   // x[b,:,t,:]  [64][8]
  __shared__ float sXA[512];  // xa          [64][8]
  const float* adjb = adj + b * 4096;
  for (int i = tid; i < 512; i += 256) {
    int n = i >> 3, f = i & 7;
    sX[i] = x[((long)(b * 64 + n) * T_ + t) * F_ + f];
  }
  __syncthreads();
  for (int i = tid; i < 512; i += 256) {
    int m = i >> 3, f = i & 7;
    float s = 0.f;
    for (int n = 0; n < 64; ++n) s += adjb[(m << 6) + n] * sX[(n << 3) + f];
    sXA[i] = s;
  }
  {
    long pbase = ((long)bl * T_ + t) * E_;
    for (int i = tid; i < 512; i += 256) {
      int m = i >> 3, f = i & 7;
      long lrow = (long)(bl * 64 + m) * T_ + t;
      tokb[lrow * E_ + f] = f2b(sX[i] + pos_em[pbase + f]);
    }
  }
  __syncthreads();
  for (int i = tid; i < 64 * 256; i += 256) {
    int m = i >> 8, d = i & 255;
    float v = 0.f;
    if (d < 248) {
      float s = gcn_b[d];
      const float* xam = &sXA[m << 3];
#pragma unroll
      for (int f = 0; f < 8; ++f) s += xam[f] * gcn_w[f * 248 + d];
      v = fmaxf(s, 0.f);
    }
    long lrow = (long)(bl * 64 + m) * T_ + t;
    G[lrow * 256 + d] = f2b(v);
  }
}

// ---------------------------------------------------------------------------
// Residency-first MFMA GEMM, SWAPPED operands (C^T fragments), vectorized
// epilogue, weight-prefetch pipelined, setprio. BM=64, BN=WAVES*64.
// emb1 (f32) indexed [ar*lde + c0 + gcol] with ar = (row/NT)*T + row%T.
// ---------------------------------------------------------------------------
template <int KCHUNKS, int WAVES>
__global__ __launch_bounds__(WAVES * 64) void block_gemm(
    const unsigned short* __restrict__ A, int lda,
    const unsigned short* __restrict__ Bt, int K, int Nact,
    const float* __restrict__ bias,
    float* Cf, unsigned short* Cb1,
    const float* __restrict__ emb1,
    const unsigned short* __restrict__ resb, const float* resf,
    int c0, int ldc, int lde, int relu) {
  __shared__ unsigned short As[64 * 256];   // 32 KB
  const int tid = threadIdx.x;
  const int lane = tid & 63, w = tid >> 6;
  const int l15 = lane & 15, lg = lane >> 4;
  const int m0 = blockIdx.x * 64;
  const int n0w = blockIdx.y * (WAVES * 64) + w * 64;

  f32x4 acc[4][4];
#pragma unroll
  for (int i = 0; i < 4; ++i)
#pragma unroll
    for (int j = 0; j < 4; ++j) acc[i][j] = (f32x4){0.f, 0.f, 0.f, 0.f};

  for (int kc = 0; kc < KCHUNKS; ++kc) {
    if (kc) __syncthreads();
#pragma unroll
    for (int j = 0; j < 32 / WAVES; ++j) {
      int idx = j * (WAVES * 64) + tid;
      int row = idx >> 5, g = idx & 31;
      int swg = (g & 24) | ((g & 7) ^ (row & 7));
      gload16(A + (long)(m0 + row) * lda + kc * 256 + swg * 8,
              &As[(j * (WAVES * 64) + w * 64) * 8]);
    }
    bf16x8 Wa[4], Wb[4], Xf[4];
    auto ldw = [&](bf16x8 (&W)[4], int ks) {
#pragma unroll
      for (int nf = 0; nf < 4; ++nf)
        W[nf] = *reinterpret_cast<const bf16x8*>(
            Bt + (long)(n0w + nf * 16 + l15) * K + kc * 256 + ks * 32 + (lg << 3));
    };
    auto ldx = [&](int ks) {
#pragma unroll
      for (int mf = 0; mf < 4; ++mf) {
        int row = (mf << 4) + l15;
        int ksg = (ks << 2) + lg;
        int sw = (ksg & 24) | ((ksg & 7) ^ (row & 7));
        Xf[mf] = *reinterpret_cast<const bf16x8*>(&As[((row << 5) + sw) * 8]);
      }
    };
    auto mm = [&](bf16x8 (&W)[4]) {
      __builtin_amdgcn_s_setprio(1);
#pragma unroll
      for (int mf = 0; mf < 4; ++mf)
#pragma unroll
        for (int nf = 0; nf < 4; ++nf)
          acc[mf][nf] = __builtin_amdgcn_mfma_f32_16x16x32_bf16(W[nf], Xf[mf], acc[mf][nf], 0, 0, 0);
      __builtin_amdgcn_s_setprio(0);
    };
    ldw(Wa, 0);                       // overlaps the staging drain below
    asm volatile("s_waitcnt vmcnt(0)" ::: "memory");
    __syncthreads();
#pragma unroll
    for (int kp = 0; kp < 4; ++kp) {
      ldw(Wb, kp * 2 + 1);
      ldx(kp * 2);
      mm(Wa);
      if (kp < 3) ldw(Wa, kp * 2 + 2);
      ldx(kp * 2 + 1);
      mm(Wb);
    }
  }

  const int cb = lg << 2;
#pragma unroll
  for (int mf = 0; mf < 4; ++mf) {
    int rr = m0 + (mf << 4) + l15;
    int ar = (rr / NT_) * T_ + (rr % T_);
    long rbase  = (long)rr * ldc + c0;
    long rbase2 = (long)rr * 256 + c0;
    long abase  = (long)ar * lde + c0;
#pragma unroll
    for (int nf = 0; nf < 4; ++nf) {
      int gcol = n0w + (nf << 4) + cb;
      if (gcol < Nact) {
        float v0 = acc[mf][nf][0], v1 = acc[mf][nf][1];
        float v2 = acc[mf][nf][2], v3 = acc[mf][nf][3];
        if (bias) {
          f32x4u b4 = *reinterpret_cast<const f32x4u*>(bias + gcol);
          v0 += b4[0]; v1 += b4[1]; v2 += b4[2]; v3 += b4[3];
        }
        if (relu) {
          v0 = fmaxf(v0, 0.f); v1 = fmaxf(v1, 0.f);
          v2 = fmaxf(v2, 0.f); v3 = fmaxf(v3, 0.f);
        }
        if (resb) {
          ushort4 rv = *reinterpret_cast<const ushort4*>(resb + rbase2 + gcol);
          v0 += b2f(rv.x); v1 += b2f(rv.y); v2 += b2f(rv.z); v3 += b2f(rv.w);
        }
        if (resf) {
          f32x4u r4 = *reinterpret_cast<const f32x4u*>(resf + rbase + gcol);
          v0 += r4[0]; v1 += r4[1]; v2 += r4[2]; v3 += r4[3];
        }
        if (emb1) {
          f32x4u e4 = *reinterpret_cast<const f32x4u*>(emb1 + abase + gcol);
          v0 += e4[0]; v1 += e4[1]; v2 += e4[2]; v3 += e4[3];
        }
        if (Cf) {
          f32x4u o; o[0] = v0; o[1] = v1; o[2] = v2; o[3] = v3;
          *reinterpret_cast<f32x4u*>(Cf + rbase + gcol) = o;
        }
        if (Cb1) {
          uint2 p = {cvtpk(v0, v1), cvtpk(v2, v3)};
          *reinterpret_cast<uint2*>(Cb1 + rbase + gcol) = p;
        }
      }
    }
  }
}

// ---------------------------------------------------------------------------
// wo GEMM + residual + LayerNorm1 fused: h1b = LN(tok + O @ wo + bo).
// BM=64, BN=256, K=256, weight-prefetch pipelined, setprio.
// ---------------------------------------------------------------------------
__global__ __launch_bounds__(256) void wo_ln_kernel(
    const unsigned short* __restrict__ A, int lda,     // O (qkv slice)
    const unsigned short* __restrict__ Wt,             // woT [256][256]
    const float* __restrict__ bias,                    // bo
    const unsigned short* __restrict__ resb,           // tokb (ld 256)
    const float* __restrict__ lng, const float* __restrict__ lnb,
    unsigned short* __restrict__ outb) {               // h1b (may alias resb)
  __shared__ unsigned short As[64 * 256];   // 32 KB
  __shared__ float red[4][4][16][2];        // 2 KB
  const int tid = threadIdx.x;
  const int lane = tid & 63, w = tid >> 6;
  const int l15 = lane & 15, lg = lane >> 4;
  const int m0 = blockIdx.x * 64;
  const int n0w = w * 64;

  f32x4 acc[4][4];
#pragma unroll
  for (int i = 0; i < 4; ++i)
#pragma unroll
    for (int j = 0; j < 4; ++j) acc[i][j] = (f32x4){0.f, 0.f, 0.f, 0.f};

#pragma unroll
  for (int j = 0; j < 8; ++j) {
    int idx = j * 256 + tid;
    int row = idx >> 5, g = idx & 31;
    int swg = (g & 24) | ((g & 7) ^ (row & 7));
    gload16(A + (long)(m0 + row) * lda + swg * 8, &As[(j * 256 + w * 64) * 8]);
  }
  bf16x8 Wa[4], Wb[4], Xf[4];
  auto ldw = [&](bf16x8 (&W)[4], int ks) {
#pragma unroll
    for (int nf = 0; nf < 4; ++nf)
      W[nf] = *reinterpret_cast<const bf16x8*>(
          Wt + (long)(n0w + nf * 16 + l15) * 256 + ks * 32 + (lg << 3));
  };
  auto ldx = [&](int ks) {
#pragma unroll
    for (int mf = 0; mf < 4; ++mf) {
      int row = (mf << 4) + l15;
      int ksg = (ks << 2) + lg;
      int sw = (ksg & 24) | ((ksg & 7) ^ (row & 7));
      Xf[mf] = *reinterpret_cast<const bf16x8*>(&As[((row << 5) + sw) * 8]);
    }
  };
  auto mm = [&](bf16x8 (&W)[4]) {
    __builtin_amdgcn_s_setprio(1);
#pragma unroll
    for (int mf = 0; mf < 4; ++mf)
#pragma unroll
      for (int nf = 0; nf < 4; ++nf)
        acc[mf][nf] = __builtin_amdgcn_mfma_f32_16x16x32_bf16(W[nf], Xf[mf], acc[mf][nf], 0, 0, 0);
    __builtin_amdgcn_s_setprio(0);
  };
  ldw(Wa, 0);
  asm volatile("s_waitcnt vmcnt(0)" ::: "memory");
  __syncthreads();
#pragma unroll
  for (int kp = 0; kp < 4; ++kp) {
    ldw(Wb, kp * 2 + 1);
    ldx(kp * 2);
    mm(Wa);
    if (kp < 3) ldw(Wa, kp * 2 + 2);
    ldx(kp * 2 + 1);
    mm(Wb);
  }

  // ---- epilogue: v = acc + bo + tok ; row stats ; LN ; bf16 store ----
  const int cb = lg << 2;
  float s[4], s2[4];
#pragma unroll
  for (int mf = 0; mf < 4; ++mf) {
    int rr = m0 + (mf << 4) + l15;
    long rbase2 = (long)rr * 256;
    s[mf] = 0.f; s2[mf] = 0.f;
#pragma unroll
    for (int nf = 0; nf < 4; ++nf) {
      int gcol = n0w + (nf << 4) + cb;
      f32x4u b4 = *reinterpret_cast<const f32x4u*>(bias + gcol);
      ushort4 rv = *reinterpret_cast<const ushort4*>(resb + rbase2 + gcol);
      float v0 = acc[mf][nf][0] + b4[0] + b2f(rv.x);
      float v1 = acc[mf][nf][1] + b4[1] + b2f(rv.y);
      float v2 = acc[mf][nf][2] + b4[2] + b2f(rv.z);
      float v3 = acc[mf][nf][3] + b4[3] + b2f(rv.w);
      acc[mf][nf][0] = v0; acc[mf][nf][1] = v1;
      acc[mf][nf][2] = v2; acc[mf][nf][3] = v3;
      s[mf] += v0 + v1 + v2 + v3;
      s2[mf] += v0 * v0 + v1 * v1 + v2 * v2 + v3 * v3;
    }
    s[mf] += __shfl_xor(s[mf], 16, 64);
    s[mf] += __shfl_xor(s[mf], 32, 64);
    s2[mf] += __shfl_xor(s2[mf], 16, 64);
    s2[mf] += __shfl_xor(s2[mf], 32, 64);
    if (lg == 0) { red[w][mf][l15][0] = s[mf]; red[w][mf][l15][1] = s2[mf]; }
  }
  __syncthreads();
#pragma unroll
  for (int mf = 0; mf < 4; ++mf) {
    float S  = red[0][mf][l15][0] + red[1][mf][l15][0] + red[2][mf][l15][0] + red[3][mf][l15][0];
    float S2 = red[0][mf][l15][1] + red[1][mf][l15][1] + red[2][mf][l15][1] + red[3][mf][l15][1];
    float mean = S * 0.00390625f;
    float var = S2 * 0.00390625f - mean * mean;
    float rs = rsqrtf(var + 1e-5f);
    int rr = m0 + (mf << 4) + l15;
    long rbase = (long)rr * 256;
#pragma unroll
    for (int nf = 0; nf < 4; ++nf) {
      int gcol = n0w + (nf << 4) + cb;
      f32x4u g4 = *reinterpret_cast<const f32x4u*>(lng + gcol);
      f32x4u t4 = *reinterpret_cast<const f32x4u*>(lnb + gcol);
      float o0 = (acc[mf][nf][0] - mean) * rs * g4[0] + t4[0];
      float o1 = (acc[mf][nf][1] - mean) * rs * g4[1] + t4[1];
      float o2 = (acc[mf][nf][2] - mean) * rs * g4[2] + t4[2];
      float o3 = (acc[mf][nf][3] - mean) * rs * g4[3] + t4[3];
      uint2 p = {cvtpk(o0, o1), cvtpk(o2, o3)};
      *reinterpret_cast<uint2*>(outb + rbase + gcol) = p;
    }
  }
}

// ---------------------------------------------------------------------------
// FUSED FF + LN2 (measured-best r15 variant): 512 threads (8 waves), 52KB LDS,
// stage-1 nf=1 depth-2 weight prefetch, stage-2 nf=2 depth-2, single fis,
// two barriers per half-chunk.
// ---------------------------------------------------------------------------
__global__ __launch_bounds__(512, 4) void ff_fused_kernel(
    const unsigned short* __restrict__ h1,   // [rows][256] bf16
    const unsigned short* __restrict__ W1,   // ff1T [1024][256]
    const unsigned short* __restrict__ W2,   // ff2T [256][1024]
    const float* __restrict__ b1, const float* __restrict__ b2,
    const float* __restrict__ lng, const float* __restrict__ lnb,
    float* __restrict__ out) {               // f32 [rows][256]
  __shared__ unsigned short h1s[64 * 256];   // 32 KB
  __shared__ unsigned short fis[64 * 128];   // 16 KB (128-col half-chunk)
  __shared__ float red[8][4][16][2];         // 4 KB
  const int tid = threadIdx.x;
  const int lane = tid & 63, w = tid >> 6;   // 8 waves
  const int l15 = lane & 15, lg = lane >> 4;
  const int m0 = blockIdx.x * 64;

  // ---- stage h1 strip (source-side XOR swizzle), 4 iters @ 512 thr ----
#pragma unroll
  for (int j = 0; j < 4; ++j) {
    int idx = j * 512 + tid;
    int row = idx >> 5, g = idx & 31;
    int swg = (g & 24) | ((g & 7) ^ (row & 7));
    gload16(h1 + (long)(m0 + row) * 256 + swg * 8, &h1s[(j * 512 + w * 64) * 8]);
  }

  f32x4 acc2[4][2];
#pragma unroll
  for (int i = 0; i < 4; ++i)
#pragma unroll
    for (int j = 0; j < 2; ++j) acc2[i][j] = (f32x4){0.f, 0.f, 0.f, 0.f};

  bf16x8 W1a, W1b, W2a[2], W2b[2], Xf[4];
  auto ldw1 = [&](bf16x8& W, int hc, int ks) {
    W = *reinterpret_cast<const bf16x8*>(
        W1 + (long)(hc * 128 + w * 16 + l15) * 256 + ks * 32 + (lg << 3));
  };
  auto ldw2 = [&](bf16x8 (&W)[2], int hc, int ks) {
#pragma unroll
    for (int nf = 0; nf < 2; ++nf)
      W[nf] = *reinterpret_cast<const bf16x8*>(
          W2 + (long)(w * 32 + nf * 16 + l15) * 1024 + hc * 128 + ks * 32 + (lg << 3));
  };
  auto ldxh = [&](int ks) {   // from h1s (32 granules/row)
#pragma unroll
    for (int mf = 0; mf < 4; ++mf) {
      int row = (mf << 4) + l15;
      int ksg = (ks << 2) + lg;
      int sw = (ksg & 24) | ((ksg & 7) ^ (row & 7));
      Xf[mf] = *reinterpret_cast<const bf16x8*>(&h1s[((row << 5) + sw) * 8]);
    }
  };
  auto ldxf = [&](int ks) {   // from fis (16 granules/row, k=128)
#pragma unroll
    for (int mf = 0; mf < 4; ++mf) {
      int row = (mf << 4) + l15;
      int ksg = (ks << 2) + lg;
      int sw = (ksg & 8) | ((ksg & 7) ^ (row & 7));
      Xf[mf] = *reinterpret_cast<const bf16x8*>(&fis[((row << 4) + sw) * 8]);
    }
  };

  const int cb = lg << 2;
  bool first = true;
  for (int hc = 0; hc < 8; ++hc) {
    // ---- stage 1: acc1 = h1 @ ff1[:, hc*128 + w*16 .. +15] (pipelined) ----
    f32x4 acc1[4];
#pragma unroll
    for (int i = 0; i < 4; ++i) acc1[i] = (f32x4){0.f, 0.f, 0.f, 0.f};
    ldw1(W1a, hc, 0);
    if (first) {
      asm volatile("s_waitcnt vmcnt(1)" ::: "memory");  // h1s staged (W1a in flight)
      __syncthreads();
      first = false;
    }
#pragma unroll
    for (int kp = 0; kp < 4; ++kp) {
      ldw1(W1b, hc, kp * 2 + 1);
      ldxh(kp * 2);
      __builtin_amdgcn_s_setprio(1);
#pragma unroll
      for (int mf = 0; mf < 4; ++mf)
        acc1[mf] = __builtin_amdgcn_mfma_f32_16x16x32_bf16(W1a, Xf[mf], acc1[mf], 0, 0, 0);
      __builtin_amdgcn_s_setprio(0);
      if (kp < 3) ldw1(W1a, hc, kp * 2 + 2);
      ldxh(kp * 2 + 1);
      __builtin_amdgcn_s_setprio(1);
#pragma unroll
      for (int mf = 0; mf < 4; ++mf)
        acc1[mf] = __builtin_amdgcn_mfma_f32_16x16x32_bf16(W1b, Xf[mf], acc1[mf], 0, 0, 0);
      __builtin_amdgcn_s_setprio(0);
    }
    if (hc) __syncthreads();   // prior stage-2 reads of fis done
    // relu + bias -> bf16 -> fis (granule-XOR, half-chunk local cols 0..127)
#pragma unroll
    for (int mf = 0; mf < 4; ++mf) {
      int row = (mf << 4) + l15;
      int col = w * 16 + cb;               // 0..127 within half-chunk
      f32x4u b4 = *reinterpret_cast<const f32x4u*>(b1 + hc * 128 + col);
      float v0 = fmaxf(acc1[mf][0] + b4[0], 0.f);
      float v1 = fmaxf(acc1[mf][1] + b4[1], 0.f);
      float v2 = fmaxf(acc1[mf][2] + b4[2], 0.f);
      float v3 = fmaxf(acc1[mf][3] + b4[3], 0.f);
      int g = col >> 3;                    // 0..15
      int swg = (g & 8) | ((g & 7) ^ (row & 7));
      uint2 p = {cvtpk(v0, v1), cvtpk(v2, v3)};
      *reinterpret_cast<uint2*>(&fis[((row << 4) + swg) * 8 + (col & 7)]) = p;
    }
    ldw2(W2a, hc, 0);          // prefetch stage-2 weights during barrier
    __syncthreads();
    // ---- stage 2: acc2 += fis_half @ ff2[hc*128.., :] (4 ks, pipelined) ----
#pragma unroll
    for (int kp = 0; kp < 2; ++kp) {
      ldw2(W2b, hc, kp * 2 + 1);
      ldxf(kp * 2);
      __builtin_amdgcn_s_setprio(1);
#pragma unroll
      for (int mf = 0; mf < 4; ++mf)
#pragma unroll
        for (int nf = 0; nf < 2; ++nf)
          acc2[mf][nf] = __builtin_amdgcn_mfma_f32_16x16x32_bf16(W2a[nf], Xf[mf], acc2[mf][nf], 0, 0, 0);
      __builtin_amdgcn_s_setprio(0);
      if (kp < 1) ldw2(W2a, hc, kp * 2 + 2);
      ldxf(kp * 2 + 1);
      __builtin_amdgcn_s_setprio(1);
#pragma unroll
      for (int mf = 0; mf < 4; ++mf)
#pragma unroll
        for (int nf = 0; nf < 2; ++nf)
          acc2[mf][nf] = __builtin_amdgcn_mfma_f32_16x16x32_bf16(W2b[nf], Xf[mf], acc2[mf][nf], 0, 0, 0);
      __builtin_amdgcn_s_setprio(0);
    }
  }

  // ---- epilogue: v = acc2 + b2 + h1 ; LN2 ; f32 store ----
  float s[4], s2[4];
#pragma unroll
  for (int mf = 0; mf < 4; ++mf) {
    int row = (mf << 4) + l15;
    s[mf] = 0.f; s2[mf] = 0.f;
#pragma unroll
    for (int nf = 0; nf < 2; ++nf) {
      int gcol = w * 32 + (nf << 4) + cb;
      f32x4u b4 = *reinterpret_cast<const f32x4u*>(b2 + gcol);
      int g = gcol >> 3;
      int swg = (g & 24) | ((g & 7) ^ (row & 7));
      ushort4 rv = *reinterpret_cast<const ushort4*>(&h1s[((row << 5) + swg) * 8 + (gcol & 7)]);
      float v0 = acc2[mf][nf][0] + b4[0] + b2f(rv.x);
      float v1 = acc2[mf][nf][1] + b4[1] + b2f(rv.y);
      float v2 = acc2[mf][nf][2] + b4[2] + b2f(rv.z);
      float v3 = acc2[mf][nf][3] + b4[3] + b2f(rv.w);
      acc2[mf][nf][0] = v0; acc2[mf][nf][1] = v1;
      acc2[mf][nf][2] = v2; acc2[mf][nf][3] = v3;
      s[mf] += v0 + v1 + v2 + v3;
      s2[mf] += v0 * v0 + v1 * v1 + v2 * v2 + v3 * v3;
    }
    s[mf] += __shfl_xor(s[mf], 16, 64);
    s[mf] += __shfl_xor(s[mf], 32, 64);
    s2[mf] += __shfl_xor(s2[mf], 16, 64);
    s2[mf] += __shfl_xor(s2[mf], 32, 64);
    if (lg == 0) { red[w][mf][l15][0] = s[mf]; red[w][mf][l15][1] = s2[mf]; }
  }
  __syncthreads();
#pragma unroll
  for (int mf = 0; mf < 4; ++mf) {
    float S = 0.f, S2 = 0.f;
#pragma unroll
    for (int ww = 0; ww < 8; ++ww) { S += red[ww][mf][l15][0]; S2 += red[ww][mf][l15][1]; }
    float mean = S * 0.00390625f;
    float var = S2 * 0.00390625f - mean * mean;
    float rs = rsqrtf(var + 1e-5f);
    int rr = m0 + (mf << 4) + l15;
    long rbase = (long)rr * 256;
#pragma unroll
    for (int nf = 0; nf < 2; ++nf) {
      int gcol = w * 32 + (nf << 4) + cb;
      f32x4u g4 = *reinterpret_cast<const f32x4u*>(lng + gcol);
      f32x4u t4 = *reinterpret_cast<const f32x4u*>(lnb + gcol);
      f32x4u o;
      o[0] = (acc2[mf][nf][0] - mean) * rs * g4[0] + t4[0];
      o[1] = (acc2[mf][nf][1] - mean) * rs * g4[1] + t4[1];
      o[2] = (acc2[mf][nf][2] - mean) * rs * g4[2] + t4[2];
      o[3] = (acc2[mf][nf][3] - mean) * rs * g4[3] + t4[3];
      *reinterpret_cast<f32x4u*>(out + rbase + gcol) = o;
    }
  }
}

// ---------------------------------------------------------------------------
// MFMA attention: one block (4 waves) per (bn, h), QKV interleaved ld=LDQ_.
// ---------------------------------------------------------------------------
__global__ __launch_bounds__(256) void attn_mfma_kernel(unsigned short* QKV) {
  int blk = blockIdx.x;
  int bn = blk >> 3, h = blk & 7;
  int tid = threadIdx.x;
  int lane = tid & 63, w = tid >> 6;

  __shared__ unsigned short Kfr[11 * 512];    // fragment-linear K tiles
  __shared__ unsigned short VT[32][200];      // V^T (dh x key), pad
  __shared__ unsigned short Pb[4][16][200];   // per-wave P buffers

  const long qbase = (long)bn * T_ * LDQ_ + h * DH_;
  const unsigned short* Kg = QKV + qbase + 256;
  const unsigned short* V  = QKV + qbase + 512;
  const unsigned short* Q  = QKV + qbase;
  unsigned short* O = QKV + qbase;
  int l15 = lane & 15, lg = lane >> 4;

  for (int kt = w; kt < 11; kt += 4) {
    gload16(Kg + (long)(kt * 16 + l15) * LDQ_ + (lg << 3), &Kfr[kt * 512]);
  }
  for (int i = tid; i < T_ * 4; i += 256) {
    int t = i >> 2, seg = (i & 3) << 3;
    uint4 vv = *reinterpret_cast<const uint4*>(V + (long)t * LDQ_ + seg);
    const unsigned short* vs = (const unsigned short*)&vv;
#pragma unroll
    for (int j = 0; j < 8; ++j) VT[seg + j][t] = vs[j];
  }
  for (int i = tid; i < 32 * 32; i += 256) VT[i >> 5][168 + (i & 31)] = 0;
  {
    unsigned short* pflat = &Pb[0][0][0];
    for (int i = tid; i < 64 * 24; i += 256)
      pflat[(i / 24) * 200 + 176 + (i % 24)] = 0;
  }
  __syncthreads();

  const float scale = 0.17677669529663687f;  // 1/sqrt(32)
  unsigned short* Pw = &Pb[w][0][0];

  for (int it = 0; it < 3; ++it) {
    int qt = w + it * 4;
    if (qt > 10) break;
    bf16x8 af = *reinterpret_cast<const bf16x8*>(
        Q + (long)(qt * 16 + l15) * LDQ_ + (lg << 3));
    f32x4 s[11];
#pragma unroll
    for (int kt = 0; kt < 11; ++kt) {
      bf16x8 bf = *reinterpret_cast<const bf16x8*>(&Kfr[kt * 512 + lane * 8]);
      s[kt] = __builtin_amdgcn_mfma_f32_16x16x32_bf16(
          af, bf, (f32x4){0.f, 0.f, 0.f, 0.f}, 0, 0, 0);
    }
    bool ok10 = (l15 < 8);
    float inv_l[4];
#pragma unroll
    for (int r = 0; r < 4; ++r) {
      float mx = -1e30f;
#pragma unroll
      for (int kt = 0; kt < 10; ++kt) mx = fmaxf(mx, s[kt][r] * scale);
      if (ok10) mx = fmaxf(mx, s[10][r] * scale);
#pragma unroll
      for (int off = 1; off < 16; off <<= 1) mx = fmaxf(mx, __shfl_xor(mx, off, 64));
      float pv[11];
      float ls = 0.f;
#pragma unroll
      for (int kt = 0; kt < 11; ++kt) {
        bool valid = (kt < 10) || ok10;
        float p = valid ? __expf(s[kt][r] * scale - mx) : 0.f;
        pv[kt] = p;
        ls += p;
      }
#pragma unroll
      for (int off = 1; off < 16; off <<= 1) ls += __shfl_xor(ls, off, 64);
      inv_l[r] = 1.f / ls;
      int prow = (lg << 2) + r;
#pragma unroll
      for (int kt = 0; kt < 11; ++kt)
        Pw[prow * 200 + kt * 16 + l15] = f2b(pv[kt]);
    }
    asm volatile("s_waitcnt lgkmcnt(0)" ::: "memory");
    __builtin_amdgcn_sched_barrier(0);
    f32x4 o0 = (f32x4){0.f, 0.f, 0.f, 0.f};
    f32x4 o1 = (f32x4){0.f, 0.f, 0.f, 0.f};
#pragma unroll
    for (int ks = 0; ks < 6; ++ks) {
      bf16x8 pf = *reinterpret_cast<const bf16x8*>(&Pw[l15 * 200 + ks * 32 + (lg << 3)]);
      bf16x8 v0 = *reinterpret_cast<const bf16x8*>(&VT[l15][ks * 32 + (lg << 3)]);
      bf16x8 v1 = *reinterpret_cast<const bf16x8*>(&VT[16 + l15][ks * 32 + (lg << 3)]);
      o0 = __builtin_amdgcn_mfma_f32_16x16x32_bf16(pf, v0, o0, 0, 0, 0);
      o1 = __builtin_amdgcn_mfma_f32_16x16x32_bf16(pf, v1, o1, 0, 0, 0);
    }
    int rg = lg << 2;
#pragma unroll
    for (int r = 0; r < 4; ++r) {
      int q = qt * 16 + rg + r;
      if (q < T_) {
        long ob = (long)q * LDQ_;
        O[ob + l15]      = f2b(o0[r] * inv_l[r]);
        O[ob + 16 + l15] = f2b(o1[r] * inv_l[r]);
      }
    }
  }
}

// ---------------------------------------------------------------------------
extern "C" void kernel_launch(void* const* d_in, const int* in_sizes, int n_in,
                              void* d_out, int out_size, void* d_ws, size_t ws_size,
                              hipStream_t stream) {
  const float* x      = (const float*)d_in[0];
  const float* locs   = (const float*)d_in[1];
  const float* pos_em = (const float*)d_in[2];
  const float* per_em = (const float*)d_in[3];
  const float* gcn_w  = (const float*)d_in[4];
  const float* gcn_b  = (const float*)d_in[5];
  const float* fc1_w  = (const float*)d_in[6];
  const float* fc1_b  = (const float*)d_in[7];
  const float* wq = (const float*)d_in[8];
  const float* bq = (const float*)d_in[9];
  const float* wk = (const float*)d_in[10];
  const float* bk = (const float*)d_in[11];
  const float* wv = (const float*)d_in[12];
  const float* bv = (const float*)d_in[13];
  const float* wo = (const float*)d_in[14];
  const float* bo = (const float*)d_in[15];
  const float* ln1_g = (const float*)d_in[16];
  const float* ln1_b = (const float*)d_in[17];
  const float* ln2_g = (const float*)d_in[18];
  const float* ln2_b = (const float*)d_in[19];
  const float* ff1_w = (const float*)d_in[20];
  const float* ff1_b = (const float*)d_in[21];
  const float* ff2_w = (const float*)d_in[22];
  const float* ff2_b = (const float*)d_in[23];
  float* out = (float*)d_out;

  // ---- workspace layout ---------------------------------------------------
  const size_t ADJ_BYTES = 1u << 20;
  const size_t WB_BYTES  = 16u << 20;   // weights + perb + perqv
  int CB = 16;
  while (CB > 1) {
    if (ADJ_BYTES + WB_BYTES + (size_t)CB * NT_ * 2048 <= ws_size) break;
    CB >>= 1;
  }
  char* ws = (char*)d_ws;
  float* adj = (float*)ws;
  unsigned short* wslab = (unsigned short*)(ws + ADJ_BYTES);
  unsigned short* fc1T  = wslab;                        // [256][256]
  unsigned short* wqkvT = wslab + 65536;                // [768][256] (wq|wk|wv)
  unsigned short* woT   = wslab + 65536 + 196608;       // [256][256]
  unsigned short* ff1T  = wslab + 65536 + 196608 + 65536;          // [1024][256]
  unsigned short* ff2T  = wslab + 65536 + 196608 + 65536 + 262144; // [256][1024]
  float* bqk = (float*)(ws + ADJ_BYTES + 1900544);      // [512] concat bias
  unsigned short* perb = (unsigned short*)(ws + ADJ_BYTES + (2u << 20));  // [2688][256] bf16
  float* perqv = (float*)(ws + ADJ_BYTES + (4u << 20));                   // [2688][768] f32

  unsigned short* tokb = (unsigned short*)(ws + ADJ_BYTES + WB_BYTES);
  unsigned short* qkv  = tokb + (size_t)CB * NT_ * 256; // [rows][768] Q|K|V
  unsigned short* h1b  = tokb;                          // bf16 h1 (over tokb)

  adj_kernel<<<B_, 64, 0, stream>>>(locs, adj);
  convw_kernel<<<256, 256, 0, stream>>>(fc1_w, fc1T, 248, 248, 256, 256);
  convw_kernel<<<256, 256, 0, stream>>>(wq, wqkvT, 256, 256, 256, 256);
  convw_kernel<<<256, 256, 0, stream>>>(wk, wqkvT + 65536, 256, 256, 256, 256);
  convw_kernel<<<256, 256, 0, stream>>>(wv, wqkvT + 2 * 65536, 256, 256, 256, 256);
  convw_kernel<<<256, 256, 0, stream>>>(wo, woT, 256, 256, 256, 256);
  convw_kernel<<<1024, 256, 0, stream>>>(ff1_w, ff1T, 256, 1024, 256, 1024);
  convw_kernel<<<1024, 256, 0, stream>>>(ff2_w, ff2T, 1024, 256, 1024, 256);
  cvtb_kernel<<<BT_, 256, 0, stream>>>(per_em, perb, BT_ * 256);
  hipMemcpyAsync(bqk, bq, 256 * sizeof(float), hipMemcpyDeviceToDevice, stream);
  hipMemcpyAsync(bqk + 256, bk, 256 * sizeof(float), hipMemcpyDeviceToDevice, stream);
  // perq[BT][512] = per_em @ (wq|wk) + bqk   (f32; tiny GEMM, M=2688, ldc=768->512)
  block_gemm<1, 8><<<dim3(BT_ / 64, 1), 512, 0, stream>>>(
      perb, 256, wqkvT, 256, 512, bqk, perqv, nullptr, nullptr,
      nullptr, nullptr, 0, 512, 256, 0);

  for (int b0 = 0; b0 < B_; b0 += CB) {
    const int rows = CB * NT_;        // multiple of 64
    const int GX = rows / 64;         // 64-row blocks
    const float* pos_c = pos_em + (long)b0 * T_ * E_;
    const float* perq_c = perqv + (long)b0 * T_ * 512;
    float* out_c = out + (long)b0 * NT_ * E_;
    unsigned short* G = qkv;          // GCN hidden lives in qkv area until consumed

    gcn_kernel<<<CB * T_, 256, 0, stream>>>(x, adj, gcn_w, gcn_b, pos_c,
                                            G, tokb, b0);
    // fc1 -> tokb[:,8:256] (+pos)
    block_gemm<1, 4><<<dim3(GX, 1), 256, 0, stream>>>(
        G, 256, fc1T, 256, 248, fc1_b, nullptr, tokb, pos_c,
        nullptr, nullptr, 8, 256, 256, 0);
    // fused Q|K (N=512) from tokb -> qkv[:, 0:512]; perq adds per-term+bias
    block_gemm<1, 8><<<dim3(GX, 1), 512, 0, stream>>>(
        tokb, 256, wqkvT, 256, 512, nullptr, nullptr, qkv, perq_c,
        nullptr, nullptr, 0, LDQ_, 512, 0);
    // V from tokb -> qkv[:, 512:768]
    block_gemm<1, 4><<<dim3(GX, 1), 256, 0, stream>>>(
        tokb, 256, wqkvT + 2 * 65536, 256, 256, bv, nullptr, qkv, nullptr,
        nullptr, nullptr, 512, LDQ_, 256, 0);
    // attention (O in-place over Q slice of qkv)
    attn_mfma_kernel<<<CB * N_ * H_, 256, 0, stream>>>(qkv);
    // wo + residual + LN1 fused: h1b = LN(tokb + O@wo + bo)
    wo_ln_kernel<<<GX, 256, 0, stream>>>(qkv, LDQ_, woT, bo, tokb,
                                         ln1_g, ln1_b, h1b);
    // FUSED FF + LN2: out_c = LN2(h1 + relu(h1@ff1+b1)@ff2 + b2), 8-wave
    ff_fused_kernel<<<GX, 512, 0, stream>>>(h1b, ff1T, ff2T, ff1_b, ff2_b,
                                            ln2_g, ln2_b, out_c);
  }
}

// Round 24
// 1077.373 us; speedup vs baseline: 1.0252x; 1.0156x over previous
//
#include <hip/hip_runtime.h>
#include <hip/hip_bf16.h>

// Problem dims
constexpr int B_  = 16;
constexpr int N_  = 64;     // stations
constexpr int T_  = 168;    // seq
constexpr int F_  = 8;      // raw features
constexpr int E_  = 256;    // dmodel
constexpr int H_  = 8;      // heads
constexpr int DH_ = 32;     // head dim
constexpr int NT_ = N_ * T_;           // 10752 (rows per batch)
constexpr int LDQ_ = 768;              // interleaved Q|K|V row stride
constexpr int BT_ = B_ * T_;           // 2688 embedding rows

typedef __bf16 bf16x8 __attribute__((ext_vector_type(8)));
typedef float  f32x4  __attribute__((ext_vector_type(4)));
typedef float  f32x4u __attribute__((ext_vector_type(4), aligned(4)));

__device__ __forceinline__ unsigned short f2b(float f) {
  union { float f; unsigned int u; } v; v.f = f;
  unsigned int r = (v.u + 0x7FFFu + ((v.u >> 16) & 1u)) >> 16;
  return (unsigned short)r;
}
__device__ __forceinline__ float b2f(unsigned short h) {
  union { unsigned int u; float f; } v; v.u = ((unsigned int)h) << 16;
  return v.f;
}
__device__ __forceinline__ unsigned int cvtpk(float lo, float hi) {
  unsigned int r;
  asm("v_cvt_pk_bf16_f32 %0, %1, %2" : "=v"(r) : "v"(lo), "v"(hi));
  return r;
}
__device__ __forceinline__ void gload16(const void* g, void* l) {
  __builtin_amdgcn_global_load_lds(
      (const __attribute__((address_space(1))) unsigned int*)g,
      (__attribute__((address_space(3))) unsigned int*)l, 16, 0, 0);
}

// ---------------------------------------------------------------------------
// adjacency  a[b][m][n] = 0.5*(w_norm[m][n] + (m==n))
// ---------------------------------------------------------------------------
__global__ void adj_kernel(const float* __restrict__ locs, float* __restrict__ a) {
  int b = blockIdx.x;
  int m = threadIdx.x;  // 64 threads
  __shared__ float lx[64], ly[64];
  lx[m] = locs[(b * 64 + m) * 2 + 0];
  ly[m] = locs[(b * 64 + m) * 2 + 1];
  __syncthreads();
  float x = lx[m], y = ly[m];
  float sum = 0.f;
  for (int n = 0; n < 64; ++n) {
    float dx = x - lx[n], dy = y - ly[n];
    float d = sqrtf(dx * dx + dy * dy + 1e-12f);
    sum += (n == m) ? 0.f : 1.f / d;
  }
  float inv = 0.5f / sum;
  for (int n = 0; n < 64; ++n) {
    float dx = x - lx[n], dy = y - ly[n];
    float d = sqrtf(dx * dx + dy * dy + 1e-12f);
    float w = (n == m) ? 0.5f : inv / d;
    a[(b * 64 + m) * 64 + n] = w;
  }
}

// ---------------------------------------------------------------------------
// MERGED preamble: all weight conversions + per_em bf16 + bias concat in ONE
// dispatch (grid.y = task, early-exit on range). Replaces 7 convw + cvtb +
// 2 D2D memcpy graph nodes.
// ---------------------------------------------------------------------------
__global__ __launch_bounds__(256) void prep_kernel(
    const float* __restrict__ fc1_w, const float* __restrict__ wq,
    const float* __restrict__ wk, const float* __restrict__ wv,
    const float* __restrict__ wo, const float* __restrict__ ff1_w,
    const float* __restrict__ ff2_w, const float* __restrict__ per_em,
    const float* __restrict__ bq, const float* __restrict__ bk,
    unsigned short* __restrict__ fc1T, unsigned short* __restrict__ wqkvT,
    unsigned short* __restrict__ woT, unsigned short* __restrict__ ff1T,
    unsigned short* __restrict__ ff2T, unsigned short* __restrict__ perb,
    float* __restrict__ bqk) {
  const int task = blockIdx.y;
  const int idx = blockIdx.x * 256 + threadIdx.x;
  auto conv = [&](const float* in, unsigned short* outT, int K, int N, int Kp, int Np) {
    if (idx < Np * Kp) {
      int n = idx / Kp, k = idx % Kp;
      float v = (k < K && n < N) ? in[(long)k * N + n] : 0.f;
      outT[idx] = f2b(v);
    }
  };
  switch (task) {
    case 0: conv(fc1_w, fc1T, 248, 248, 256, 256); break;
    case 1: conv(wq, wqkvT, 256, 256, 256, 256); break;
    case 2: conv(wk, wqkvT + 65536, 256, 256, 256, 256); break;
    case 3: conv(wv, wqkvT + 2 * 65536, 256, 256, 256, 256); break;
    case 4: conv(wo, woT, 256, 256, 256, 256); break;
    case 5: conv(ff1_w, ff1T, 256, 1024, 256, 1024); break;
    case 6: conv(ff2_w, ff2T, 1024, 256, 1024, 256); break;
    case 7: if (idx < BT_ * 256) perb[idx] = f2b(per_em[idx]); break;
    case 8:
      if (idx < 256) bqk[idx] = bq[idx];
      else if (idx < 512) bqk[idx] = bk[idx - 256];
      break;
  }
}

// ---------------------------------------------------------------------------
// GCN front-end for one (b,t) in chunk [b0, b0+CB)
// ---------------------------------------------------------------------------
__global__ __launch_bounds__(256) void gcn_kernel(
    const float* __restrict__ x, const float* __restrict__ adj,
    const float* __restrict__ gcn_w, const float* __restrict__ gcn_b,
    const float* __restrict__ pos_em,
    unsigned short* __restrict__ G, unsigned short* __restrict__ tokb, int b0) {
  int bl = blockIdx.x / T_;
  int t = blockIdx.x % T_;
  int b = b0 + bl;
  int tid = threadIdx.x;
  __shared__ float sX[512];   // x[b,:,t,:]  [64][8]
  __shared__ float sXA[512];  // xa          [64][8]
  const float* adjb = adj + b * 4096;
  for (int i = tid; i < 512; i += 256) {
    int n = i >> 3, f = i & 7;
    sX[i] = x[((long)(b * 64 + n) * T_ + t) * F_ + f];
  }
  __syncthreads();
  for (int i = tid; i < 512; i += 256) {
    int m = i >> 3, f = i & 7;
    float s = 0.f;
    for (int n = 0; n < 64; ++n) s += adjb[(m << 6) + n] * sX[(n << 3) + f];
    sXA[i] = s;
  }
  {
    long pbase = ((long)bl * T_ + t) * E_;
    for (int i = tid; i < 512; i += 256) {
      int m = i >> 3, f = i & 7;
      long lrow = (long)(bl * 64 + m) * T_ + t;
      tokb[lrow * E_ + f] = f2b(sX[i] + pos_em[pbase + f]);
    }
  }
  __syncthreads();
  for (int i = tid; i < 64 * 256; i += 256) {
    int m = i >> 8, d = i & 255;
    float v = 0.f;
    if (d < 248) {
      float s = gcn_b[d];
      const float* xam = &sXA[m << 3];
#pragma unroll
      for (int f = 0; f < 8; ++f) s += xam[f] * gcn_w[f * 248 + d];
      v = fmaxf(s, 0.f);
    }
    long lrow = (long)(bl * 64 + m) * T_ + t;
    G[lrow * 256 + d] = f2b(v);
  }
}

// ---------------------------------------------------------------------------
// Residency-first MFMA GEMM, SWAPPED operands (C^T fragments), vectorized
// epilogue, weight-prefetch pipelined, setprio. BM=64, BN=WAVES*64.
// emb1 (f32) indexed [ar*lde + c0 + gcol] with ar = (row/NT)*T + row%T.
// ---------------------------------------------------------------------------
template <int KCHUNKS, int WAVES>
__global__ __launch_bounds__(WAVES * 64) void block_gemm(
    const unsigned short* __restrict__ A, int lda,
    const unsigned short* __restrict__ Bt, int K, int Nact,
    const float* __restrict__ bias,
    float* Cf, unsigned short* Cb1,
    const float* __restrict__ emb1,
    const unsigned short* __restrict__ resb, const float* resf,
    int c0, int ldc, int lde, int relu) {
  __shared__ unsigned short As[64 * 256];   // 32 KB
  const int tid = threadIdx.x;
  const int lane = tid & 63, w = tid >> 6;
  const int l15 = lane & 15, lg = lane >> 4;
  const int m0 = blockIdx.x * 64;
  const int n0w = blockIdx.y * (WAVES * 64) + w * 64;

  f32x4 acc[4][4];
#pragma unroll
  for (int i = 0; i < 4; ++i)
#pragma unroll
    for (int j = 0; j < 4; ++j) acc[i][j] = (f32x4){0.f, 0.f, 0.f, 0.f};

  for (int kc = 0; kc < KCHUNKS; ++kc) {
    if (kc) __syncthreads();
#pragma unroll
    for (int j = 0; j < 32 / WAVES; ++j) {
      int idx = j * (WAVES * 64) + tid;
      int row = idx >> 5, g = idx & 31;
      int swg = (g & 24) | ((g & 7) ^ (row & 7));
      gload16(A + (long)(m0 + row) * lda + kc * 256 + swg * 8,
              &As[(j * (WAVES * 64) + w * 64) * 8]);
    }
    bf16x8 Wa[4], Wb[4], Xf[4];
    auto ldw = [&](bf16x8 (&W)[4], int ks) {
#pragma unroll
      for (int nf = 0; nf < 4; ++nf)
        W[nf] = *reinterpret_cast<const bf16x8*>(
            Bt + (long)(n0w + nf * 16 + l15) * K + kc * 256 + ks * 32 + (lg << 3));
    };
    auto ldx = [&](int ks) {
#pragma unroll
      for (int mf = 0; mf < 4; ++mf) {
        int row = (mf << 4) + l15;
        int ksg = (ks << 2) + lg;
        int sw = (ksg & 24) | ((ksg & 7) ^ (row & 7));
        Xf[mf] = *reinterpret_cast<const bf16x8*>(&As[((row << 5) + sw) * 8]);
      }
    };
    auto mm = [&](bf16x8 (&W)[4]) {
      __builtin_amdgcn_s_setprio(1);
#pragma unroll
      for (int mf = 0; mf < 4; ++mf)
#pragma unroll
        for (int nf = 0; nf < 4; ++nf)
          acc[mf][nf] = __builtin_amdgcn_mfma_f32_16x16x32_bf16(W[nf], Xf[mf], acc[mf][nf], 0, 0, 0);
      __builtin_amdgcn_s_setprio(0);
    };
    ldw(Wa, 0);                       // overlaps the staging drain below
    asm volatile("s_waitcnt vmcnt(0)" ::: "memory");
    __syncthreads();
#pragma unroll
    for (int kp = 0; kp < 4; ++kp) {
      ldw(Wb, kp * 2 + 1);
      ldx(kp * 2);
      mm(Wa);
      if (kp < 3) ldw(Wa, kp * 2 + 2);
      ldx(kp * 2 + 1);
      mm(Wb);
    }
  }

  const int cb = lg << 2;
#pragma unroll
  for (int mf = 0; mf < 4; ++mf) {
    int rr = m0 + (mf << 4) + l15;
    int ar = (rr / NT_) * T_ + (rr % T_);
    long rbase  = (long)rr * ldc + c0;
    long rbase2 = (long)rr * 256 + c0;
    long abase  = (long)ar * lde + c0;
#pragma unroll
    for (int nf = 0; nf < 4; ++nf) {
      int gcol = n0w + (nf << 4) + cb;
      if (gcol < Nact) {
        float v0 = acc[mf][nf][0], v1 = acc[mf][nf][1];
        float v2 = acc[mf][nf][2], v3 = acc[mf][nf][3];
        if (bias) {
          f32x4u b4 = *reinterpret_cast<const f32x4u*>(bias + gcol);
          v0 += b4[0]; v1 += b4[1]; v2 += b4[2]; v3 += b4[3];
        }
        if (relu) {
          v0 = fmaxf(v0, 0.f); v1 = fmaxf(v1, 0.f);
          v2 = fmaxf(v2, 0.f); v3 = fmaxf(v3, 0.f);
        }
        if (resb) {
          ushort4 rv = *reinterpret_cast<const ushort4*>(resb + rbase2 + gcol);
          v0 += b2f(rv.x); v1 += b2f(rv.y); v2 += b2f(rv.z); v3 += b2f(rv.w);
        }
        if (resf) {
          f32x4u r4 = *reinterpret_cast<const f32x4u*>(resf + rbase + gcol);
          v0 += r4[0]; v1 += r4[1]; v2 += r4[2]; v3 += r4[3];
        }
        if (emb1) {
          f32x4u e4 = *reinterpret_cast<const f32x4u*>(emb1 + abase + gcol);
          v0 += e4[0]; v1 += e4[1]; v2 += e4[2]; v3 += e4[3];
        }
        if (Cf) {
          f32x4u o; o[0] = v0; o[1] = v1; o[2] = v2; o[3] = v3;
          *reinterpret_cast<f32x4u*>(Cf + rbase + gcol) = o;
        }
        if (Cb1) {
          uint2 p = {cvtpk(v0, v1), cvtpk(v2, v3)};
          *reinterpret_cast<uint2*>(Cb1 + rbase + gcol) = p;
        }
      }
    }
  }
}

// ---------------------------------------------------------------------------
// wo GEMM + residual + LayerNorm1 fused: h1b = LN(tok + O @ wo + bo).
// BM=64, BN=256, K=256, weight-prefetch pipelined, setprio.
// ---------------------------------------------------------------------------
__global__ __launch_bounds__(256) void wo_ln_kernel(
    const unsigned short* __restrict__ A, int lda,     // O (qkv slice)
    const unsigned short* __restrict__ Wt,             // woT [256][256]
    const float* __restrict__ bias,                    // bo
    const unsigned short* __restrict__ resb,           // tokb (ld 256)
    const float* __restrict__ lng, const float* __restrict__ lnb,
    unsigned short* __restrict__ outb) {               // h1b (may alias resb)
  __shared__ unsigned short As[64 * 256];   // 32 KB
  __shared__ float red[4][4][16][2];        // 2 KB
  const int tid = threadIdx.x;
  const int lane = tid & 63, w = tid >> 6;
  const int l15 = lane & 15, lg = lane >> 4;
  const int m0 = blockIdx.x * 64;
  const int n0w = w * 64;

  f32x4 acc[4][4];
#pragma unroll
  for (int i = 0; i < 4; ++i)
#pragma unroll
    for (int j = 0; j < 4; ++j) acc[i][j] = (f32x4){0.f, 0.f, 0.f, 0.f};

#pragma unroll
  for (int j = 0; j < 8; ++j) {
    int idx = j * 256 + tid;
    int row = idx >> 5, g = idx & 31;
    int swg = (g & 24) | ((g & 7) ^ (row & 7));
    gload16(A + (long)(m0 + row) * lda + swg * 8, &As[(j * 256 + w * 64) * 8]);
  }
  bf16x8 Wa[4], Wb[4], Xf[4];
  auto ldw = [&](bf16x8 (&W)[4], int ks) {
#pragma unroll
    for (int nf = 0; nf < 4; ++nf)
      W[nf] = *reinterpret_cast<const bf16x8*>(
          Wt + (long)(n0w + nf * 16 + l15) * 256 + ks * 32 + (lg << 3));
  };
  auto ldx = [&](int ks) {
#pragma unroll
    for (int mf = 0; mf < 4; ++mf) {
      int row = (mf << 4) + l15;
      int ksg = (ks << 2) + lg;
      int sw = (ksg & 24) | ((ksg & 7) ^ (row & 7));
      Xf[mf] = *reinterpret_cast<const bf16x8*>(&As[((row << 5) + sw) * 8]);
    }
  };
  auto mm = [&](bf16x8 (&W)[4]) {
    __builtin_amdgcn_s_setprio(1);
#pragma unroll
    for (int mf = 0; mf < 4; ++mf)
#pragma unroll
      for (int nf = 0; nf < 4; ++nf)
        acc[mf][nf] = __builtin_amdgcn_mfma_f32_16x16x32_bf16(W[nf], Xf[mf], acc[mf][nf], 0, 0, 0);
    __builtin_amdgcn_s_setprio(0);
  };
  ldw(Wa, 0);
  asm volatile("s_waitcnt vmcnt(0)" ::: "memory");
  __syncthreads();
#pragma unroll
  for (int kp = 0; kp < 4; ++kp) {
    ldw(Wb, kp * 2 + 1);
    ldx(kp * 2);
    mm(Wa);
    if (kp < 3) ldw(Wa, kp * 2 + 2);
    ldx(kp * 2 + 1);
    mm(Wb);
  }

  // ---- epilogue: v = acc + bo + tok ; row stats ; LN ; bf16 store ----
  const int cb = lg << 2;
  float s[4], s2[4];
#pragma unroll
  for (int mf = 0; mf < 4; ++mf) {
    int rr = m0 + (mf << 4) + l15;
    long rbase2 = (long)rr * 256;
    s[mf] = 0.f; s2[mf] = 0.f;
#pragma unroll
    for (int nf = 0; nf < 4; ++nf) {
      int gcol = n0w + (nf << 4) + cb;
      f32x4u b4 = *reinterpret_cast<const f32x4u*>(bias + gcol);
      ushort4 rv = *reinterpret_cast<const ushort4*>(resb + rbase2 + gcol);
      float v0 = acc[mf][nf][0] + b4[0] + b2f(rv.x);
      float v1 = acc[mf][nf][1] + b4[1] + b2f(rv.y);
      float v2 = acc[mf][nf][2] + b4[2] + b2f(rv.z);
      float v3 = acc[mf][nf][3] + b4[3] + b2f(rv.w);
      acc[mf][nf][0] = v0; acc[mf][nf][1] = v1;
      acc[mf][nf][2] = v2; acc[mf][nf][3] = v3;
      s[mf] += v0 + v1 + v2 + v3;
      s2[mf] += v0 * v0 + v1 * v1 + v2 * v2 + v3 * v3;
    }
    s[mf] += __shfl_xor(s[mf], 16, 64);
    s[mf] += __shfl_xor(s[mf], 32, 64);
    s2[mf] += __shfl_xor(s2[mf], 16, 64);
    s2[mf] += __shfl_xor(s2[mf], 32, 64);
    if (lg == 0) { red[w][mf][l15][0] = s[mf]; red[w][mf][l15][1] = s2[mf]; }
  }
  __syncthreads();
#pragma unroll
  for (int mf = 0; mf < 4; ++mf) {
    float S  = red[0][mf][l15][0] + red[1][mf][l15][0] + red[2][mf][l15][0] + red[3][mf][l15][0];
    float S2 = red[0][mf][l15][1] + red[1][mf][l15][1] + red[2][mf][l15][1] + red[3][mf][l15][1];
    float mean = S * 0.00390625f;
    float var = S2 * 0.00390625f - mean * mean;
    float rs = rsqrtf(var + 1e-5f);
    int rr = m0 + (mf << 4) + l15;
    long rbase = (long)rr * 256;
#pragma unroll
    for (int nf = 0; nf < 4; ++nf) {
      int gcol = n0w + (nf << 4) + cb;
      f32x4u g4 = *reinterpret_cast<const f32x4u*>(lng + gcol);
      f32x4u t4 = *reinterpret_cast<const f32x4u*>(lnb + gcol);
      float o0 = (acc[mf][nf][0] - mean) * rs * g4[0] + t4[0];
      float o1 = (acc[mf][nf][1] - mean) * rs * g4[1] + t4[1];
      float o2 = (acc[mf][nf][2] - mean) * rs * g4[2] + t4[2];
      float o3 = (acc[mf][nf][3] - mean) * rs * g4[3] + t4[3];
      uint2 p = {cvtpk(o0, o1), cvtpk(o2, o3)};
      *reinterpret_cast<uint2*>(outb + rbase + gcol) = p;
    }
  }
}

// ---------------------------------------------------------------------------
// FUSED FF + LN2 (measured-best r15 variant): 512 threads (8 waves), 52KB LDS,
// stage-1 nf=1 depth-2 weight prefetch, stage-2 nf=2 depth-2, single fis,
// two barriers per half-chunk.
// ---------------------------------------------------------------------------
__global__ __launch_bounds__(512, 4) void ff_fused_kernel(
    const unsigned short* __restrict__ h1,   // [rows][256] bf16
    const unsigned short* __restrict__ W1,   // ff1T [1024][256]
    const unsigned short* __restrict__ W2,   // ff2T [256][1024]
    const float* __restrict__ b1, const float* __restrict__ b2,
    const float* __restrict__ lng, const float* __restrict__ lnb,
    float* __restrict__ out) {               // f32 [rows][256]
  __shared__ unsigned short h1s[64 * 256];   // 32 KB
  __shared__ unsigned short fis[64 * 128];   // 16 KB (128-col half-chunk)
  __shared__ float red[8][4][16][2];         // 4 KB
  const int tid = threadIdx.x;
  const int lane = tid & 63, w = tid >> 6;   // 8 waves
  const int l15 = lane & 15, lg = lane >> 4;
  const int m0 = blockIdx.x * 64;

  // ---- stage h1 strip (source-side XOR swizzle), 4 iters @ 512 thr ----
#pragma unroll
  for (int j = 0; j < 4; ++j) {
    int idx = j * 512 + tid;
    int row = idx >> 5, g = idx & 31;
    int swg = (g & 24) | ((g & 7) ^ (row & 7));
    gload16(h1 + (long)(m0 + row) * 256 + swg * 8, &h1s[(j * 512 + w * 64) * 8]);
  }

  f32x4 acc2[4][2];
#pragma unroll
  for (int i = 0; i < 4; ++i)
#pragma unroll
    for (int j = 0; j < 2; ++j) acc2[i][j] = (f32x4){0.f, 0.f, 0.f, 0.f};

  bf16x8 W1a, W1b, W2a[2], W2b[2], Xf[4];
  auto ldw1 = [&](bf16x8& W, int hc, int ks) {
    W = *reinterpret_cast<const bf16x8*>(
        W1 + (long)(hc * 128 + w * 16 + l15) * 256 + ks * 32 + (lg << 3));
  };
  auto ldw2 = [&](bf16x8 (&W)[2], int hc, int ks) {
#pragma unroll
    for (int nf = 0; nf < 2; ++nf)
      W[nf] = *reinterpret_cast<const bf16x8*>(
          W2 + (long)(w * 32 + nf * 16 + l15) * 1024 + hc * 128 + ks * 32 + (lg << 3));
  };
  auto ldxh = [&](int ks) {   // from h1s (32 granules/row)
#pragma unroll
    for (int mf = 0; mf < 4; ++mf) {
      int row = (mf << 4) + l15;
      int ksg = (ks << 2) + lg;
      int sw = (ksg & 24) | ((ksg & 7) ^ (row & 7));
      Xf[mf] = *reinterpret_cast<const bf16x8*>(&h1s[((row << 5) + sw) * 8]);
    }
  };
  auto ldxf = [&](int ks) {   // from fis (16 granules/row, k=128)
#pragma unroll
    for (int mf = 0; mf < 4; ++mf) {
      int row = (mf << 4) + l15;
      int ksg = (ks << 2) + lg;
      int sw = (ksg & 8) | ((ksg & 7) ^ (row & 7));
      Xf[mf] = *reinterpret_cast<const bf16x8*>(&fis[((row << 4) + sw) * 8]);
    }
  };

  const int cb = lg << 2;
  bool first = true;
  for (int hc = 0; hc < 8; ++hc) {
    // ---- stage 1: acc1 = h1 @ ff1[:, hc*128 + w*16 .. +15] (pipelined) ----
    f32x4 acc1[4];
#pragma unroll
    for (int i = 0; i < 4; ++i) acc1[i] = (f32x4){0.f, 0.f, 0.f, 0.f};
    ldw1(W1a, hc, 0);
    if (first) {
      asm volatile("s_waitcnt vmcnt(1)" ::: "memory");  // h1s staged (W1a in flight)
      __syncthreads();
      first = false;
    }
#pragma unroll
    for (int kp = 0; kp < 4; ++kp) {
      ldw1(W1b, hc, kp * 2 + 1);
      ldxh(kp * 2);
      __builtin_amdgcn_s_setprio(1);
#pragma unroll
      for (int mf = 0; mf < 4; ++mf)
        acc1[mf] = __builtin_amdgcn_mfma_f32_16x16x32_bf16(W1a, Xf[mf], acc1[mf], 0, 0, 0);
      __builtin_amdgcn_s_setprio(0);
      if (kp < 3) ldw1(W1a, hc, kp * 2 + 2);
      ldxh(kp * 2 + 1);
      __builtin_amdgcn_s_setprio(1);
#pragma unroll
      for (int mf = 0; mf < 4; ++mf)
        acc1[mf] = __builtin_amdgcn_mfma_f32_16x16x32_bf16(W1b, Xf[mf], acc1[mf], 0, 0, 0);
      __builtin_amdgcn_s_setprio(0);
    }
    if (hc) __syncthreads();   // prior stage-2 reads of fis done
    // relu + bias -> bf16 -> fis (granule-XOR, half-chunk local cols 0..127)
#pragma unroll
    for (int mf = 0; mf < 4; ++mf) {
      int row = (mf << 4) + l15;
      int col = w * 16 + cb;               // 0..127 within half-chunk
      f32x4u b4 = *reinterpret_cast<const f32x4u*>(b1 + hc * 128 + col);
      float v0 = fmaxf(acc1[mf][0] + b4[0], 0.f);
      float v1 = fmaxf(acc1[mf][1] + b4[1], 0.f);
      float v2 = fmaxf(acc1[mf][2] + b4[2], 0.f);
      float v3 = fmaxf(acc1[mf][3] + b4[3], 0.f);
      int g = col >> 3;                    // 0..15
      int swg = (g & 8) | ((g & 7) ^ (row & 7));
      uint2 p = {cvtpk(v0, v1), cvtpk(v2, v3)};
      *reinterpret_cast<uint2*>(&fis[((row << 4) + swg) * 8 + (col & 7)]) = p;
    }
    ldw2(W2a, hc, 0);          // prefetch stage-2 weights during barrier
    __syncthreads();
    // ---- stage 2: acc2 += fis_half @ ff2[hc*128.., :] (4 ks, pipelined) ----
#pragma unroll
    for (int kp = 0; kp < 2; ++kp) {
      ldw2(W2b, hc, kp * 2 + 1);
      ldxf(kp * 2);
      __builtin_amdgcn_s_setprio(1);
#pragma unroll
      for (int mf = 0; mf < 4; ++mf)
#pragma unroll
        for (int nf = 0; nf < 2; ++nf)
          acc2[mf][nf] = __builtin_amdgcn_mfma_f32_16x16x32_bf16(W2a[nf], Xf[mf], acc2[mf][nf], 0, 0, 0);
      __builtin_amdgcn_s_setprio(0);
      if (kp < 1) ldw2(W2a, hc, kp * 2 + 2);
      ldxf(kp * 2 + 1);
      __builtin_amdgcn_s_setprio(1);
#pragma unroll
      for (int mf = 0; mf < 4; ++mf)
#pragma unroll
        for (int nf = 0; nf < 2; ++nf)
          acc2[mf][nf] = __builtin_amdgcn_mfma_f32_16x16x32_bf16(W2b[nf], Xf[mf], acc2[mf][nf], 0, 0, 0);
      __builtin_amdgcn_s_setprio(0);
    }
  }

  // ---- epilogue: v = acc2 + b2 + h1 ; LN2 ; f32 store ----
  float s[4], s2[4];
#pragma unroll
  for (int mf = 0; mf < 4; ++mf) {
    int row = (mf << 4) + l15;
    s[mf] = 0.f; s2[mf] = 0.f;
#pragma unroll
    for (int nf = 0; nf < 2; ++nf) {
      int gcol = w * 32 + (nf << 4) + cb;
      f32x4u b4 = *reinterpret_cast<const f32x4u*>(b2 + gcol);
      int g = gcol >> 3;
      int swg = (g & 24) | ((g & 7) ^ (row & 7));
      ushort4 rv = *reinterpret_cast<const ushort4*>(&h1s[((row << 5) + swg) * 8 + (gcol & 7)]);
      float v0 = acc2[mf][nf][0] + b4[0] + b2f(rv.x);
      float v1 = acc2[mf][nf][1] + b4[1] + b2f(rv.y);
      float v2 = acc2[mf][nf][2] + b4[2] + b2f(rv.z);
      float v3 = acc2[mf][nf][3] + b4[3] + b2f(rv.w);
      acc2[mf][nf][0] = v0; acc2[mf][nf][1] = v1;
      acc2[mf][nf][2] = v2; acc2[mf][nf][3] = v3;
      s[mf] += v0 + v1 + v2 + v3;
      s2[mf] += v0 * v0 + v1 * v1 + v2 * v2 + v3 * v3;
    }
    s[mf] += __shfl_xor(s[mf], 16, 64);
    s[mf] += __shfl_xor(s[mf], 32, 64);
    s2[mf] += __shfl_xor(s2[mf], 16, 64);
    s2[mf] += __shfl_xor(s2[mf], 32, 64);
    if (lg == 0) { red[w][mf][l15][0] = s[mf]; red[w][mf][l15][1] = s2[mf]; }
  }
  __syncthreads();
#pragma unroll
  for (int mf = 0; mf < 4; ++mf) {
    float S = 0.f, S2 = 0.f;
#pragma unroll
    for (int ww = 0; ww < 8; ++ww) { S += red[ww][mf][l15][0]; S2 += red[ww][mf][l15][1]; }
    float mean = S * 0.00390625f;
    float var = S2 * 0.00390625f - mean * mean;
    float rs = rsqrtf(var + 1e-5f);
    int rr = m0 + (mf << 4) + l15;
    long rbase = (long)rr * 256;
#pragma unroll
    for (int nf = 0; nf < 2; ++nf) {
      int gcol = w * 32 + (nf << 4) + cb;
      f32x4u g4 = *reinterpret_cast<const f32x4u*>(lng + gcol);
      f32x4u t4 = *reinterpret_cast<const f32x4u*>(lnb + gcol);
      f32x4u o;
      o[0] = (acc2[mf][nf][0] - mean) * rs * g4[0] + t4[0];
      o[1] = (acc2[mf][nf][1] - mean) * rs * g4[1] + t4[1];
      o[2] = (acc2[mf][nf][2] - mean) * rs * g4[2] + t4[2];
      o[3] = (acc2[mf][nf][3] - mean) * rs * g4[3] + t4[3];
      *reinterpret_cast<f32x4u*>(out + rbase + gcol) = o;
    }
  }
}

// ---------------------------------------------------------------------------
// MFMA attention: one block (4 waves) per (bn, h), QKV interleaved ld=LDQ_.
// ---------------------------------------------------------------------------
__global__ __launch_bounds__(256) void attn_mfma_kernel(unsigned short* QKV) {
  int blk = blockIdx.x;
  int bn = blk >> 3, h = blk & 7;
  int tid = threadIdx.x;
  int lane = tid & 63, w = tid >> 6;

  __shared__ unsigned short Kfr[11 * 512];    // fragment-linear K tiles
  __shared__ unsigned short VT[32][200];      // V^T (dh x key), pad
  __shared__ unsigned short Pb[4][16][200];   // per-wave P buffers

  const long qbase = (long)bn * T_ * LDQ_ + h * DH_;
  const unsigned short* Kg = QKV + qbase + 256;
  const unsigned short* V  = QKV + qbase + 512;
  const unsigned short* Q  = QKV + qbase;
  unsigned short* O = QKV + qbase;
  int l15 = lane & 15, lg = lane >> 4;

  for (int kt = w; kt < 11; kt += 4) {
    gload16(Kg + (long)(kt * 16 + l15) * LDQ_ + (lg << 3), &Kfr[kt * 512]);
  }
  for (int i = tid; i < T_ * 4; i += 256) {
    int t = i >> 2, seg = (i & 3) << 3;
    uint4 vv = *reinterpret_cast<const uint4*>(V + (long)t * LDQ_ + seg);
    const unsigned short* vs = (const unsigned short*)&vv;
#pragma unroll
    for (int j = 0; j < 8; ++j) VT[seg + j][t] = vs[j];
  }
  for (int i = tid; i < 32 * 32; i += 256) VT[i >> 5][168 + (i & 31)] = 0;
  {
    unsigned short* pflat = &Pb[0][0][0];
    for (int i = tid; i < 64 * 24; i += 256)
      pflat[(i / 24) * 200 + 176 + (i % 24)] = 0;
  }
  __syncthreads();

  const float scale = 0.17677669529663687f;  // 1/sqrt(32)
  unsigned short* Pw = &Pb[w][0][0];

  for (int it = 0; it < 3; ++it) {
    int qt = w + it * 4;
    if (qt > 10) break;
    bf16x8 af = *reinterpret_cast<const bf16x8*>(
        Q + (long)(qt * 16 + l15) * LDQ_ + (lg << 3));
    f32x4 s[11];
#pragma unroll
    for (int kt = 0; kt < 11; ++kt) {
      bf16x8 bf = *reinterpret_cast<const bf16x8*>(&Kfr[kt * 512 + lane * 8]);
      s[kt] = __builtin_amdgcn_mfma_f32_16x16x32_bf16(
          af, bf, (f32x4){0.f, 0.f, 0.f, 0.f}, 0, 0, 0);
    }
    bool ok10 = (l15 < 8);
    float inv_l[4];
#pragma unroll
    for (int r = 0; r < 4; ++r) {
      float mx = -1e30f;
#pragma unroll
      for (int kt = 0; kt < 10; ++kt) mx = fmaxf(mx, s[kt][r] * scale);
      if (ok10) mx = fmaxf(mx, s[10][r] * scale);
#pragma unroll
      for (int off = 1; off < 16; off <<= 1) mx = fmaxf(mx, __shfl_xor(mx, off, 64));
      float pv[11];
      float ls = 0.f;
#pragma unroll
      for (int kt = 0; kt < 11; ++kt) {
        bool valid = (kt < 10) || ok10;
        float p = valid ? __expf(s[kt][r] * scale - mx) : 0.f;
        pv[kt] = p;
        ls += p;
      }
#pragma unroll
      for (int off = 1; off < 16; off <<= 1) ls += __shfl_xor(ls, off, 64);
      inv_l[r] = 1.f / ls;
      int prow = (lg << 2) + r;
#pragma unroll
      for (int kt = 0; kt < 11; ++kt)
        Pw[prow * 200 + kt * 16 + l15] = f2b(pv[kt]);
    }
    asm volatile("s_waitcnt lgkmcnt(0)" ::: "memory");
    __builtin_amdgcn_sched_barrier(0);
    f32x4 o0 = (f32x4){0.f, 0.f, 0.f, 0.f};
    f32x4 o1 = (f32x4){0.f, 0.f, 0.f, 0.f};
#pragma unroll
    for (int ks = 0; ks < 6; ++ks) {
      bf16x8 pf = *reinterpret_cast<const bf16x8*>(&Pw[l15 * 200 + ks * 32 + (lg << 3)]);
      bf16x8 v0 = *reinterpret_cast<const bf16x8*>(&VT[l15][ks * 32 + (lg << 3)]);
      bf16x8 v1 = *reinterpret_cast<const bf16x8*>(&VT[16 + l15][ks * 32 + (lg << 3)]);
      o0 = __builtin_amdgcn_mfma_f32_16x16x32_bf16(pf, v0, o0, 0, 0, 0);
      o1 = __builtin_amdgcn_mfma_f32_16x16x32_bf16(pf, v1, o1, 0, 0, 0);
    }
    int rg = lg << 2;
#pragma unroll
    for (int r = 0; r < 4; ++r) {
      int q = qt * 16 + rg + r;
      if (q < T_) {
        long ob = (long)q * LDQ_;
        O[ob + l15]      = f2b(o0[r] * inv_l[r]);
        O[ob + 16 + l15] = f2b(o1[r] * inv_l[r]);
      }
    }
  }
}

// ---------------------------------------------------------------------------
extern "C" void kernel_launch(void* const* d_in, const int* in_sizes, int n_in,
                              void* d_out, int out_size, void* d_ws, size_t ws_size,
                              hipStream_t stream) {
  const float* x      = (const float*)d_in[0];
  const float* locs   = (const float*)d_in[1];
  const float* pos_em = (const float*)d_in[2];
  const float* per_em = (const float*)d_in[3];
  const float* gcn_w  = (const float*)d_in[4];
  const float* gcn_b  = (const float*)d_in[5];
  const float* fc1_w  = (const float*)d_in[6];
  const float* fc1_b  = (const float*)d_in[7];
  const float* wq = (const float*)d_in[8];
  const float* bq = (const float*)d_in[9];
  const float* wk = (const float*)d_in[10];
  const float* bk = (const float*)d_in[11];
  const float* wv = (const float*)d_in[12];
  const float* bv = (const float*)d_in[13];
  const float* wo = (const float*)d_in[14];
  const float* bo = (const float*)d_in[15];
  const float* ln1_g = (const float*)d_in[16];
  const float* ln1_b = (const float*)d_in[17];
  const float* ln2_g = (const float*)d_in[18];
  const float* ln2_b = (const float*)d_in[19];
  const float* ff1_w = (const float*)d_in[20];
  const float* ff1_b = (const float*)d_in[21];
  const float* ff2_w = (const float*)d_in[22];
  const float* ff2_b = (const float*)d_in[23];
  float* out = (float*)d_out;

  // ---- workspace layout ---------------------------------------------------
  const size_t ADJ_BYTES = 1u << 20;
  const size_t WB_BYTES  = 16u << 20;   // weights + perb + perqv
  int CB = 16;
  while (CB > 1) {
    if (ADJ_BYTES + WB_BYTES + (size_t)CB * NT_ * 2048 <= ws_size) break;
    CB >>= 1;
  }
  char* ws = (char*)d_ws;
  float* adj = (float*)ws;
  unsigned short* wslab = (unsigned short*)(ws + ADJ_BYTES);
  unsigned short* fc1T  = wslab;                        // [256][256]
  unsigned short* wqkvT = wslab + 65536;                // [768][256] (wq|wk|wv)
  unsigned short* woT   = wslab + 65536 + 196608;       // [256][256]
  unsigned short* ff1T  = wslab + 65536 + 196608 + 65536;          // [1024][256]
  unsigned short* ff2T  = wslab + 65536 + 196608 + 65536 + 262144; // [256][1024]
  float* bqk = (float*)(ws + ADJ_BYTES + 1900544);      // [512] concat bias
  unsigned short* perb = (unsigned short*)(ws + ADJ_BYTES + (2u << 20));  // [2688][256] bf16
  float* perqv = (float*)(ws + ADJ_BYTES + (4u << 20));                   // [2688][512] f32

  unsigned short* tokb = (unsigned short*)(ws + ADJ_BYTES + WB_BYTES);
  unsigned short* qkv  = tokb + (size_t)CB * NT_ * 256; // [rows][768] Q|K|V
  unsigned short* h1b  = tokb;                          // bf16 h1 (over tokb)

  adj_kernel<<<B_, 64, 0, stream>>>(locs, adj);
  // merged preamble: all conversions + bias concat in ONE dispatch
  prep_kernel<<<dim3(BT_, 9), 256, 0, stream>>>(
      fc1_w, wq, wk, wv, wo, ff1_w, ff2_w, per_em, bq, bk,
      fc1T, wqkvT, woT, ff1T, ff2T, perb, bqk);
  // perq[BT][512] = per_em @ (wq|wk) + bqk   (f32; tiny GEMM, M=2688)
  block_gemm<1, 8><<<dim3(BT_ / 64, 1), 512, 0, stream>>>(
      perb, 256, wqkvT, 256, 512, bqk, perqv, nullptr, nullptr,
      nullptr, nullptr, 0, 512, 256, 0);

  for (int b0 = 0; b0 < B_; b0 += CB) {
    const int rows = CB * NT_;        // multiple of 64
    const int GX = rows / 64;         // 64-row blocks
    const float* pos_c = pos_em + (long)b0 * T_ * E_;
    const float* perq_c = perqv + (long)b0 * T_ * 512;
    float* out_c = out + (long)b0 * NT_ * E_;
    unsigned short* G = qkv;          // GCN hidden lives in qkv area until consumed

    gcn_kernel<<<CB * T_, 256, 0, stream>>>(x, adj, gcn_w, gcn_b, pos_c,
                                            G, tokb, b0);
    // fc1 -> tokb[:,8:256] (+pos)
    block_gemm<1, 4><<<dim3(GX, 1), 256, 0, stream>>>(
        G, 256, fc1T, 256, 248, fc1_b, nullptr, tokb, pos_c,
        nullptr, nullptr, 8, 256, 256, 0);
    // fused Q|K (N=512) from tokb -> qkv[:, 0:512]; perq adds per-term+bias
    block_gemm<1, 8><<<dim3(GX, 1), 512, 0, stream>>>(
        tokb, 256, wqkvT, 256, 512, nullptr, nullptr, qkv, perq_c,
        nullptr, nullptr, 0, LDQ_, 512, 0);
    // V from tokb -> qkv[:, 512:768]
    block_gemm<1, 4><<<dim3(GX, 1), 256, 0, stream>>>(
        tokb, 256, wqkvT + 2 * 65536, 256, 256, bv, nullptr, qkv, nullptr,
        nullptr, nullptr, 512, LDQ_, 256, 0);
    // attention (O in-place over Q slice of qkv)
    attn_mfma_kernel<<<CB * N_ * H_, 256, 0, stream>>>(qkv);
    // wo + residual + LN1 fused: h1b = LN(tokb + O@wo + bo)
    wo_ln_kernel<<<GX, 256, 0, stream>>>(qkv, LDQ_, woT, bo, tokb,
                                         ln1_g, ln1_b, h1b);
    // FUSED FF + LN2: out_c = LN2(h1 + relu(h1@ff1+b1)@ff2 + b2), 8-wave
    ff_fused_kernel<<<GX, 512, 0, stream>>>(h1b, ff1T, ff2T, ff1_b, ff2_b,
                                            ln2_g, ln2_b, out_c);
  }
}